// Round 1
// baseline (323.372 us; speedup 1.0000x reference)
//
#include <hip/hip_runtime.h>
#include <math.h>

#define Bz 8
#define NQ 4096
#define NKV 4096
#define Cc 256
#define KNN 16
#define Hh 32
#define EPSf 1e-5f
#define SLOPEf 0.2f

typedef unsigned long long u64t;
typedef unsigned int u32t;

// ---- workspace layout (bytes) ----
#define OFF_W1AS 0u                       // 32*256 f32 (alpha1-folded w1a)
#define OFF_W1DS (OFF_W1AS + 32768u)      // 32*256 f32 (alpha1-folded (w1b-w1a))
#define OFF_W2T  (OFF_W1DS + 32768u)      // 32*256 f32 w2t[h][c] = alpha2[c]*w2[c][h]
#define OFF_C1   (OFF_W2T + 32768u)       // 32 f32: b1 - alpha1*m1
#define OFF_B2F  (OFF_C1 + 1024u)         // 256 f32: b2 - alpha2*m2
#define OFF_KVP  (OFF_B2F + 2048u)        // 8*4096 float4 kv xyz (w = |k|^2)
#define OFF_QP   (OFF_KVP + 524288u)      // 8*4096 float4 q xyz (w = |q|^2 + 1)
#define OFF_KVS  (OFF_QP + 524288u)       // 8*4096*32 f32
#define OFF_QADD (OFF_KVS + 4194304u)     // 8*4096*32 f32
#define OFF_PD   (OFF_QADD + 4194304u)    // 8*4096*NSL*16 f64 per-slice sorted keys

__device__ __forceinline__ float leaky(float x) { return fmaxf(x, SLOPEf * x); }

// f64 comparators: CAS = v_min_f64 + v_max_f64 (2 instrs); MN2 = v_min_f64 (1)
#define CASD(A, B) { double lo_ = fmin(A, B); double hi_ = fmax(A, B); (A) = lo_; (B) = hi_; }
#define MND(A, B)  { (A) = fmin(A, B); }

// Batcher odd-even mergesort, 16 elements, 63 comparators (c0..c15 ascending)
#define SORTC16 \
  CASD(c0,c1) CASD(c2,c3) CASD(c4,c5) CASD(c6,c7) CASD(c8,c9) CASD(c10,c11) CASD(c12,c13) CASD(c14,c15) \
  CASD(c0,c2) CASD(c4,c6) CASD(c8,c10) CASD(c12,c14) CASD(c1,c3) CASD(c5,c7) CASD(c9,c11) CASD(c13,c15) \
  CASD(c1,c2) CASD(c5,c6) CASD(c9,c10) CASD(c13,c14) \
  CASD(c0,c4) CASD(c8,c12) CASD(c1,c5) CASD(c9,c13) CASD(c2,c6) CASD(c10,c14) CASD(c3,c7) CASD(c11,c15) \
  CASD(c2,c4) CASD(c10,c12) CASD(c3,c5) CASD(c11,c13) \
  CASD(c1,c2) CASD(c3,c4) CASD(c5,c6) CASD(c9,c10) CASD(c11,c12) CASD(c13,c14) \
  CASD(c0,c8) CASD(c1,c9) CASD(c2,c10) CASD(c3,c11) CASD(c4,c12) CASD(c5,c13) CASD(c6,c14) CASD(c7,c15) \
  CASD(c4,c8) CASD(c5,c9) CASD(c6,c10) CASD(c7,c11) \
  CASD(c2,c4) CASD(c3,c5) CASD(c6,c8) CASD(c7,c9) CASD(c10,c12) CASD(c11,c13) \
  CASD(c1,c2) CASD(c3,c4) CASD(c5,c6) CASD(c7,c8) CASD(c9,c10) CASD(c11,c12) CASD(c13,c14)

// keep-lowest-16 of sorted b (asc) U sorted c (asc): reversed pairwise min, bitonic clean
#define MERGE16 \
  MND(b0,c15) MND(b1,c14) MND(b2,c13) MND(b3,c12) MND(b4,c11) MND(b5,c10) MND(b6,c9) MND(b7,c8) \
  MND(b8,c7) MND(b9,c6) MND(b10,c5) MND(b11,c4) MND(b12,c3) MND(b13,c2) MND(b14,c1) MND(b15,c0) \
  CASD(b0,b8) CASD(b1,b9) CASD(b2,b10) CASD(b3,b11) CASD(b4,b12) CASD(b5,b13) CASD(b6,b14) CASD(b7,b15) \
  CASD(b0,b4) CASD(b1,b5) CASD(b2,b6) CASD(b3,b7) CASD(b8,b12) CASD(b9,b13) CASD(b10,b14) CASD(b11,b15) \
  CASD(b0,b2) CASD(b1,b3) CASD(b4,b6) CASD(b5,b7) CASD(b8,b10) CASD(b9,b11) CASD(b12,b14) CASD(b13,b15) \
  CASD(b0,b1) CASD(b2,b3) CASD(b4,b5) CASD(b6,b7) CASD(b8,b9) CASD(b10,b11) CASD(b12,b13) CASD(b14,b15)

// ---------------- kernel 0: fold weights + pack xyz as float4 ----------------
__global__ __launch_bounds__(256) void k_prep(
    const float* __restrict__ qxyz, const float* __restrict__ kxyz,
    const float* __restrict__ w1, const float* __restrict__ g1,
    const float* __restrict__ b1, const float* __restrict__ m1,
    const float* __restrict__ v1, const float* __restrict__ w2,
    const float* __restrict__ g2, const float* __restrict__ b2,
    const float* __restrict__ m2, const float* __restrict__ v2,
    char* __restrict__ ws) {
  int t = threadIdx.x;
  if (blockIdx.x == 0) {
    __shared__ float a1[Hh], a2c[Cc];
    if (t < Hh) a1[t] = g1[t] / sqrtf(v1[t] + EPSf);
    if (t < Cc) a2c[t] = g2[t] / sqrtf(v2[t] + EPSf);
    __syncthreads();
    float* w1as = (float*)(ws + OFF_W1AS);
    float* w1ds = (float*)(ws + OFF_W1DS);
    float* w2t  = (float*)(ws + OFF_W2T);
    float* c1   = (float*)(ws + OFF_C1);
    float* b2f  = (float*)(ws + OFF_B2F);
    for (int i = t; i < Hh * Cc; i += 256) {
      int h = i >> 8, c = i & 255;
      float wa = w1[h * 2 * Cc + c];
      float wb = w1[h * 2 * Cc + Cc + c];
      w1as[i] = a1[h] * wa;
      w1ds[i] = a1[h] * (wb - wa);
      w2t[i] = a2c[c] * w2[c * Hh + h];   // i = h*256 + c
    }
    if (t < Hh) c1[t] = b1[t] - a1[t] * m1[t];
    if (t < Cc) b2f[t] = b2[t] - a2c[t] * m2[t];
  } else {
    // pack xyz -> float4; kv.w = |k|^2, q.w = |q|^2 + 1 (positivity bias: dist >= ~1 > 0
    // so positive-f64 value order == bit order; required by OR-packed keys)
    float4* kvp = (float4*)(ws + OFF_KVP);
    float4* qp  = (float4*)(ws + OFF_QP);
    for (int i = 0; i < 2; ++i) {
      int g = (blockIdx.x - 1) * 512 + i * 256 + t;  // 0..65535
      if (g < Bz * NKV) {
        const float* src = kxyz + (size_t)g * 3;
        float4 v; v.x = src[0]; v.y = src[1]; v.z = src[2];
        v.w = fmaf(v.x, v.x, fmaf(v.y, v.y, v.z * v.z));
        kvp[g] = v;
      } else {
        int g2i = g - Bz * NKV;
        const float* src = qxyz + (size_t)g2i * 3;
        float4 v; v.x = src[0]; v.y = src[1]; v.z = src[2];
        v.w = fmaf(v.x, v.x, fmaf(v.y, v.y, v.z * v.z)) + 1.0f;
        qp[g2i] = v;
      }
    }
  }
}

// ------------- kernel 1 (fused mid): even blocks = per-slice exact top-16 (f64 keys);
// odd blocks = kvs/qadd feature GEMMs. The two are independent; interleaving them on each
// CU lets feat's f32-FMA + memory phases fill sel's f64-VALU idle slots (sel alone was
// 28% occupancy / 77% VALUBusy).
//
// sel key packing: key = bits((double)dist_f32) | idx. (double)dq has 29 zero low-mantissa
// bits; idx < 4096 fits in 12. Distinct f32 dists differ by >= 2^29 mantissa units, so
// f64 VALUE order == (fp32 dist, idx) lexicographic == jax top_k tie semantics (dist >= 1
// guarantees positive => value order == bit order). Saves f64 fma + f64 add per key vs
// fma-packing, and kills the 16 live id registers.
template <int SLt>
__global__ __launch_bounds__(256) void k_mid(
    const float* __restrict__ kvf, const float* __restrict__ qf,
    char* __restrict__ ws, double* __restrict__ pd) {
  constexpr int NSLt = NKV / SLt;
  constexpr int S = (NQ / 256) * NSLt * Bz;  // sel blocks
  // F = 64 * Bz * 2 = 1024 feat blocks
  __shared__ __align__(16) float smem[64 * 68 + 32 * 68];  // 26112 B; sel uses <= 16 KB as lk
  int t = threadIdx.x;
  int bid = blockIdx.x;
  bool is_sel;
  int rid;
  if (bid < 2 * S) { is_sel = !(bid & 1); rid = bid >> 1; }
  else             { is_sel = false;      rid = bid - S; }

  if (is_sel) {
    // ---- per-slice exact top-16 ----
    float4* lk = (float4*)smem;
    int qt = rid & 15;                 // NQ/256 == 16
    int s = (rid >> 4) % NSLt;
    int b = rid / (16 * NSLt);
    const float4* kvp = (const float4*)(ws + OFF_KVP) + (size_t)b * NKV + s * SLt;
    const float4* qp = (const float4*)(ws + OFF_QP);
#pragma unroll
    for (int i = 0; i < SLt / 256; ++i) lk[i * 256 + t] = kvp[i * 256 + t];
    int q = qt * 256 + t;
    float4 qv = qp[(size_t)b * NQ + q];
    float qx2 = -2.0f * qv.x, qy2 = -2.0f * qv.y, qz2 = -2.0f * qv.z, qw = qv.w;
    __syncthreads();
    int gbase = s * SLt;
    double b0 = 1e300, b1 = 1e300, b2 = 1e300, b3 = 1e300, b4 = 1e300, b5 = 1e300, b6 = 1e300, b7 = 1e300;
    double b8 = 1e300, b9 = 1e300, b10 = 1e300, b11 = 1e300, b12 = 1e300, b13 = 1e300, b14 = 1e300, b15 = 1e300;
#define MK(J) { float4 kv = lk[o + J]; \
  float dq = fmaf(qx2, kv.x, fmaf(qy2, kv.y, fmaf(qz2, kv.z, kv.w + qw))); \
  c##J = __longlong_as_double(__double_as_longlong((double)dq) | (long long)(ib + J)); }
#pragma unroll 2
    for (int blk = 0; blk < SLt / 16; ++blk) {
      int o = blk * 16;
      int ib = gbase + o;
      double c0, c1, c2, c3, c4, c5, c6, c7, c8, c9, c10, c11, c12, c13, c14, c15;
      MK(0) MK(1) MK(2) MK(3) MK(4) MK(5) MK(6) MK(7)
      MK(8) MK(9) MK(10) MK(11) MK(12) MK(13) MK(14) MK(15)
      SORTC16
      MERGE16
    }
#undef MK
    double* ob = pd + (((size_t)b * NQ + q) * NSLt + s) * KNN;
    ob[0] = b0; ob[1] = b1; ob[2] = b2; ob[3] = b3;
    ob[4] = b4; ob[5] = b5; ob[6] = b6; ob[7] = b7;
    ob[8] = b8; ob[9] = b9; ob[10] = b10; ob[11] = b11;
    ob[12] = b12; ob[13] = b13; ob[14] = b14; ob[15] = b15;
  } else {
    // ---- feature GEMMs: kvs = (a1*w1a)·kv_feat ; qadd = (a1*w1d)·q_feat + c1 ----
    float (*fs)[68]  = (float(*)[68])smem;
    float (*wsh)[68] = (float(*)[68])(smem + 64 * 68);
    int hh = t & 15, rr = t >> 4;
    int xb = rid & 63;
    int b = (rid >> 6) & (Bz - 1);
    int mode = rid >> 9;               // rid / (64*Bz)
    int m0 = xb * 64;
    const float* in = mode ? qf : kvf;
    const float* w = (const float*)(ws + (mode ? OFF_W1DS : OFF_W1AS));
    const float* c1 = (const float*)(ws + OFF_C1);
    float* out = (float*)(ws + (mode ? OFF_QADD : OFF_KVS));
    const float* inb = in + ((size_t)b * NKV + m0) * Cc;
    float acc[2][4] = {{0.f, 0.f, 0.f, 0.f}, {0.f, 0.f, 0.f, 0.f}};
    for (int cc = 0; cc < 4; ++cc) {
      __syncthreads();
#pragma unroll
      for (int i = 0; i < 4; ++i) {  // stage 64x64 feat tile
        int l = i * 256 + t, row = l >> 4, c4 = l & 15;
        *(float4*)&fs[row][c4 * 4] = *(const float4*)(inb + (size_t)row * Cc + cc * 64 + c4 * 4);
      }
#pragma unroll
      for (int i = 0; i < 2; ++i) {  // stage 32x64 weight tile
        int l = i * 256 + t, row = l >> 4, c4 = l & 15;
        *(float4*)&wsh[row][c4 * 4] = *(const float4*)(w + (size_t)row * Cc + cc * 64 + c4 * 4);
      }
      __syncthreads();
#pragma unroll
      for (int c4 = 0; c4 < 16; ++c4) {
        float4 w0 = *(float4*)&wsh[hh][c4 * 4];
        float4 w1v = *(float4*)&wsh[hh + 16][c4 * 4];
#pragma unroll
        for (int j = 0; j < 4; ++j) {
          float4 f = *(float4*)&fs[rr + j * 16][c4 * 4];
          acc[0][j] = fmaf(w0.x, f.x, fmaf(w0.y, f.y, fmaf(w0.z, f.z, fmaf(w0.w, f.w, acc[0][j]))));
          acc[1][j] = fmaf(w1v.x, f.x, fmaf(w1v.y, f.y, fmaf(w1v.z, f.z, fmaf(w1v.w, f.w, acc[1][j]))));
        }
      }
    }
    float add0 = mode ? c1[hh] : 0.f;
    float add1 = mode ? c1[hh + 16] : 0.f;
    float* ob = out + ((size_t)b * NKV + m0) * Hh;
#pragma unroll
    for (int j = 0; j < 4; ++j) {
      ob[(rr + j * 16) * Hh + hh] = acc[0][j] + add0;
      ob[(rr + j * 16) * Hh + hh + 16] = acc[1][j] + add1;
    }
  }
}

// ------------- kernel 2 (fused tail): merge lists -> gather+maxpool+leaky -> matvec+BN2+leaky -------------
// block = 256 threads, 64 queries. Phases: (1a) 2 threads/q merge half-lists; (1b) 1 thread/q final
// merge -> sidx; (2) 4 lanes/q gather kvs rows + maxpool + qadd + leaky -> xs (transposed);
// (3) 64 q x 4 cb-waves: y = leaky(w2t·x + b2f).
template <int NSLt>
__global__ __launch_bounds__(256) void k_tail(
    const double* __restrict__ pd, const char* __restrict__ ws_c,
    float* __restrict__ out) {
  __shared__ double mg[64][2][KNN];   // 16 KB
  __shared__ int sidx[64 * 17];       // 4.25 KB (stride-17 pad)
  __shared__ float xs[Hh * 64];       // 8 KB, transposed: xs[h][q]
  int t = threadIdx.x;
  int b = blockIdx.y, q0 = blockIdx.x * 64;

  // ---- phase 1a ----
  if (t < 128) {
    int q = t >> 1, p = t & 1;
    constexpr int half = NSLt / 2;
    const double* L = pd + (((size_t)b * NQ + q0 + q) * NSLt + (size_t)p * half) * KNN;
    double b0 = L[0], b1 = L[1], b2 = L[2], b3 = L[3], b4 = L[4], b5 = L[5], b6 = L[6], b7 = L[7];
    double b8 = L[8], b9 = L[9], b10 = L[10], b11 = L[11], b12 = L[12], b13 = L[13], b14 = L[14], b15 = L[15];
#pragma unroll
    for (int s = 1; s < half; ++s) {
      const double* C = L + (size_t)s * KNN;
      double c0 = C[0], c1 = C[1], c2 = C[2], c3 = C[3], c4 = C[4], c5 = C[5], c6 = C[6], c7 = C[7];
      double c8 = C[8], c9 = C[9], c10 = C[10], c11 = C[11], c12 = C[12], c13 = C[13], c14 = C[14], c15 = C[15];
      MERGE16
    }
    double* m = &mg[q][p][0];
    m[0] = b0; m[1] = b1; m[2] = b2; m[3] = b3; m[4] = b4; m[5] = b5; m[6] = b6; m[7] = b7;
    m[8] = b8; m[9] = b9; m[10] = b10; m[11] = b11; m[12] = b12; m[13] = b13; m[14] = b14; m[15] = b15;
  }
  __syncthreads();
  // ---- phase 1b ----
  if (t < 64) {
    const double* A = &mg[t][0][0];
    const double* C2 = &mg[t][1][0];
    double b0 = A[0], b1 = A[1], b2 = A[2], b3 = A[3], b4 = A[4], b5 = A[5], b6 = A[6], b7 = A[7];
    double b8 = A[8], b9 = A[9], b10 = A[10], b11 = A[11], b12 = A[12], b13 = A[13], b14 = A[14], b15 = A[15];
    double c0 = C2[0], c1 = C2[1], c2 = C2[2], c3 = C2[3], c4 = C2[4], c5 = C2[5], c6 = C2[6], c7 = C2[7];
    double c8 = C2[8], c9 = C2[9], c10 = C2[10], c11 = C2[11], c12 = C2[12], c13 = C2[13], c14 = C2[14], c15 = C2[15];
    MERGE16
    // OR-packed keys: idx lives in the low 12 mantissa BITS -> extract via bit-cast
    int* si = &sidx[t * 17];
    si[0] = (int)(__double_as_longlong(b0) & 4095);
    si[1] = (int)(__double_as_longlong(b1) & 4095);
    si[2] = (int)(__double_as_longlong(b2) & 4095);
    si[3] = (int)(__double_as_longlong(b3) & 4095);
    si[4] = (int)(__double_as_longlong(b4) & 4095);
    si[5] = (int)(__double_as_longlong(b5) & 4095);
    si[6] = (int)(__double_as_longlong(b6) & 4095);
    si[7] = (int)(__double_as_longlong(b7) & 4095);
    si[8] = (int)(__double_as_longlong(b8) & 4095);
    si[9] = (int)(__double_as_longlong(b9) & 4095);
    si[10] = (int)(__double_as_longlong(b10) & 4095);
    si[11] = (int)(__double_as_longlong(b11) & 4095);
    si[12] = (int)(__double_as_longlong(b12) & 4095);
    si[13] = (int)(__double_as_longlong(b13) & 4095);
    si[14] = (int)(__double_as_longlong(b14) & 4095);
    si[15] = (int)(__double_as_longlong(b15) & 4095);
  }
  __syncthreads();
  // ---- phase 2: gather + maxpool + qadd + leaky -> xs (transposed) ----
  {
    int q = t >> 2, l = t & 3;
    const float4* kvs = (const float4*)(ws_c + OFF_KVS) + (size_t)b * NKV * 8 + l * 2;
    float4 p0 = make_float4(-3.4e38f, -3.4e38f, -3.4e38f, -3.4e38f);
    float4 p1 = p0;
#pragma unroll
    for (int n = 0; n < KNN; ++n) {
      int m = sidx[q * 17 + n];
      const float4* row = kvs + (size_t)m * 8;
      float4 v0 = row[0], v1 = row[1];
      p0.x = fmaxf(p0.x, v0.x); p0.y = fmaxf(p0.y, v0.y); p0.z = fmaxf(p0.z, v0.z); p0.w = fmaxf(p0.w, v0.w);
      p1.x = fmaxf(p1.x, v1.x); p1.y = fmaxf(p1.y, v1.y); p1.z = fmaxf(p1.z, v1.z); p1.w = fmaxf(p1.w, v1.w);
    }
    const float4* qa = (const float4*)(ws_c + OFF_QADD) + ((size_t)b * NQ + q0 + q) * 8 + l * 2;
    float4 a0 = qa[0], a1 = qa[1];
    int h0 = 8 * l;
    xs[(h0 + 0) * 64 + q] = leaky(p0.x + a0.x);
    xs[(h0 + 1) * 64 + q] = leaky(p0.y + a0.y);
    xs[(h0 + 2) * 64 + q] = leaky(p0.z + a0.z);
    xs[(h0 + 3) * 64 + q] = leaky(p0.w + a0.w);
    xs[(h0 + 4) * 64 + q] = leaky(p1.x + a1.x);
    xs[(h0 + 5) * 64 + q] = leaky(p1.y + a1.y);
    xs[(h0 + 6) * 64 + q] = leaky(p1.z + a1.z);
    xs[(h0 + 7) * 64 + q] = leaky(p1.w + a1.w);
  }
  __syncthreads();
  // ---- phase 3: y = leaky(w2t · x + b2f) ----
  {
    int ql = t & 63, cb = t >> 6;  // cb wave-uniform -> w2t loads become scalar
    const float* w2t = (const float*)(ws_c + OFF_W2T);
    const float* b2f = (const float*)(ws_c + OFF_B2F);
    float xv[Hh];
#pragma unroll
    for (int h = 0; h < Hh; ++h) xv[h] = xs[h * 64 + ql];
    float4 acc[16];
#pragma unroll
    for (int c4 = 0; c4 < 16; ++c4) acc[c4] = make_float4(0.f, 0.f, 0.f, 0.f);
#pragma unroll
    for (int h = 0; h < Hh; ++h) {
      float xh = xv[h];
      const float4* wrow = (const float4*)(w2t + (size_t)h * Cc + cb * 64);
#pragma unroll
      for (int c4 = 0; c4 < 16; ++c4) {
        float4 w = wrow[c4];
        acc[c4].x = fmaf(xh, w.x, acc[c4].x);
        acc[c4].y = fmaf(xh, w.y, acc[c4].y);
        acc[c4].z = fmaf(xh, w.z, acc[c4].z);
        acc[c4].w = fmaf(xh, w.w, acc[c4].w);
      }
    }
    float* o = out + ((size_t)b * NQ + q0 + ql) * Cc + cb * 64;
    const float4* bb = (const float4*)(b2f + cb * 64);
#pragma unroll
    for (int c4 = 0; c4 < 16; ++c4) {
      float4 bv = bb[c4];
      float4 r;
      r.x = leaky(acc[c4].x + bv.x); r.y = leaky(acc[c4].y + bv.y);
      r.z = leaky(acc[c4].z + bv.z); r.w = leaky(acc[c4].w + bv.w);
      *(float4*)(o + c4 * 4) = r;
    }
  }
}

extern "C" void kernel_launch(void* const* d_in, const int* in_sizes, int n_in,
                              void* d_out, int out_size, void* d_ws, size_t ws_size,
                              hipStream_t stream) {
  const float* qf   = (const float*)d_in[0];
  const float* qxyz = (const float*)d_in[1];
  const float* kvf  = (const float*)d_in[2];
  const float* kxyz = (const float*)d_in[3];
  const float* w1 = (const float*)d_in[4];
  const float* g1 = (const float*)d_in[5];
  const float* b1 = (const float*)d_in[6];
  const float* m1 = (const float*)d_in[7];
  const float* v1 = (const float*)d_in[8];
  const float* w2 = (const float*)d_in[9];
  const float* g2 = (const float*)d_in[10];
  const float* b2 = (const float*)d_in[11];
  const float* m2 = (const float*)d_in[12];
  const float* v2 = (const float*)d_in[13];
  char* ws = (char*)d_ws;
  double* pd = (double*)(ws + OFF_PD);

  // NSL=8 needs OFF_PD + 8*4096*8*16*8 = ~42.5 MB of ws; fall back to NSL=4 otherwise.
  size_t need8 = (size_t)OFF_PD + (size_t)Bz * NQ * 8 * KNN * sizeof(double);
  bool big = ws_size >= need8;

  k_prep<<<129, 256, 0, stream>>>(qxyz, kxyz, w1, g1, b1, m1, v1, w2, g2, b2, m2, v2, ws);
  if (big) {
    // sel blocks S = 16*8*8 = 1024, feat blocks F = 1024 -> 2048, parity-interleaved
    k_mid<512><<<2048, 256, 0, stream>>>(kvf, qf, ws, pd);
    k_tail<8><<<dim3(NQ / 64, Bz), 256, 0, stream>>>(pd, ws, (float*)d_out);
  } else {
    // S = 16*4*8 = 512, F = 1024 -> 1536
    k_mid<1024><<<1536, 256, 0, stream>>>(kvf, qf, ws, pd);
    k_tail<4><<<dim3(NQ / 64, Bz), 256, 0, stream>>>(pd, ws, (float*)d_out);
  }
}

// Round 2
// 298.700 us; speedup vs baseline: 1.0826x; 1.0826x over previous
//
#include <hip/hip_runtime.h>
#include <math.h>

#define Bz 8
#define NQ 4096
#define NKV 4096
#define Cc 256
#define KNN 16
#define Hh 32
#define EPSf 1e-5f
#define SLOPEf 0.2f

typedef unsigned long long u64t;
typedef unsigned int u32t;

// ---- workspace layout (bytes) ----
#define OFF_W1AS 0u                       // 32*256 f32 (alpha1-folded w1a)
#define OFF_W1DS (OFF_W1AS + 32768u)      // 32*256 f32 (alpha1-folded (w1b-w1a))
#define OFF_W2T  (OFF_W1DS + 32768u)      // 32*256 f32 w2t[h][c] = alpha2[c]*w2[c][h]
#define OFF_C1   (OFF_W2T + 32768u)       // 32 f32: b1 - alpha1*m1
#define OFF_B2F  (OFF_C1 + 1024u)         // 256 f32: b2 - alpha2*m2
#define OFF_KVP  (OFF_B2F + 2048u)        // 8*4096 float4 kv xyz (w = |k|^2)
#define OFF_QP   (OFF_KVP + 524288u)      // 8*4096 float4 q xyz (w = |q|^2 + 1)
#define OFF_KVS  (OFF_QP + 524288u)       // 8*4096*32 f32
#define OFF_QADD (OFF_KVS + 4194304u)     // 8*4096*32 f32
#define OFF_PD   (OFF_QADD + 4194304u)    // 8*4096*NSL*16 f64 per-slice sorted keys

__device__ __forceinline__ float leaky(float x) { return fmaxf(x, SLOPEf * x); }

// f64 comparators: CAS = v_min_f64 + v_max_f64 (2 instrs); MN2 = v_min_f64 (1)
#define CASD(A, B) { double lo_ = fmin(A, B); double hi_ = fmax(A, B); (A) = lo_; (B) = hi_; }
#define MND(A, B)  { (A) = fmin(A, B); }

// Batcher odd-even mergesort, 16 elements, 63 comparators (c0..c15 ascending)
#define SORTC16 \
  CASD(c0,c1) CASD(c2,c3) CASD(c4,c5) CASD(c6,c7) CASD(c8,c9) CASD(c10,c11) CASD(c12,c13) CASD(c14,c15) \
  CASD(c0,c2) CASD(c4,c6) CASD(c8,c10) CASD(c12,c14) CASD(c1,c3) CASD(c5,c7) CASD(c9,c11) CASD(c13,c15) \
  CASD(c1,c2) CASD(c5,c6) CASD(c9,c10) CASD(c13,c14) \
  CASD(c0,c4) CASD(c8,c12) CASD(c1,c5) CASD(c9,c13) CASD(c2,c6) CASD(c10,c14) CASD(c3,c7) CASD(c11,c15) \
  CASD(c2,c4) CASD(c10,c12) CASD(c3,c5) CASD(c11,c13) \
  CASD(c1,c2) CASD(c3,c4) CASD(c5,c6) CASD(c9,c10) CASD(c11,c12) CASD(c13,c14) \
  CASD(c0,c8) CASD(c1,c9) CASD(c2,c10) CASD(c3,c11) CASD(c4,c12) CASD(c5,c13) CASD(c6,c14) CASD(c7,c15) \
  CASD(c4,c8) CASD(c5,c9) CASD(c6,c10) CASD(c7,c11) \
  CASD(c2,c4) CASD(c3,c5) CASD(c6,c8) CASD(c7,c9) CASD(c10,c12) CASD(c11,c13) \
  CASD(c1,c2) CASD(c3,c4) CASD(c5,c6) CASD(c7,c8) CASD(c9,c10) CASD(c11,c12) CASD(c13,c14)

// keep-lowest-16 of sorted b (asc) U sorted c (asc): reversed pairwise min, bitonic clean
#define MERGE16 \
  MND(b0,c15) MND(b1,c14) MND(b2,c13) MND(b3,c12) MND(b4,c11) MND(b5,c10) MND(b6,c9) MND(b7,c8) \
  MND(b8,c7) MND(b9,c6) MND(b10,c5) MND(b11,c4) MND(b12,c3) MND(b13,c2) MND(b14,c1) MND(b15,c0) \
  CASD(b0,b8) CASD(b1,b9) CASD(b2,b10) CASD(b3,b11) CASD(b4,b12) CASD(b5,b13) CASD(b6,b14) CASD(b7,b15) \
  CASD(b0,b4) CASD(b1,b5) CASD(b2,b6) CASD(b3,b7) CASD(b8,b12) CASD(b9,b13) CASD(b10,b14) CASD(b11,b15) \
  CASD(b0,b2) CASD(b1,b3) CASD(b4,b6) CASD(b5,b7) CASD(b8,b10) CASD(b9,b11) CASD(b12,b14) CASD(b13,b15) \
  CASD(b0,b1) CASD(b2,b3) CASD(b4,b5) CASD(b6,b7) CASD(b8,b9) CASD(b10,b11) CASD(b12,b13) CASD(b14,b15)

// ---------------- kernel 0: fold weights + pack xyz as float4 ----------------
__global__ __launch_bounds__(256) void k_prep(
    const float* __restrict__ qxyz, const float* __restrict__ kxyz,
    const float* __restrict__ w1, const float* __restrict__ g1,
    const float* __restrict__ b1, const float* __restrict__ m1,
    const float* __restrict__ v1, const float* __restrict__ w2,
    const float* __restrict__ g2, const float* __restrict__ b2,
    const float* __restrict__ m2, const float* __restrict__ v2,
    char* __restrict__ ws) {
  int t = threadIdx.x;
  if (blockIdx.x == 0) {
    __shared__ float a1[Hh], a2c[Cc];
    if (t < Hh) a1[t] = g1[t] / sqrtf(v1[t] + EPSf);
    if (t < Cc) a2c[t] = g2[t] / sqrtf(v2[t] + EPSf);
    __syncthreads();
    float* w1as = (float*)(ws + OFF_W1AS);
    float* w1ds = (float*)(ws + OFF_W1DS);
    float* w2t  = (float*)(ws + OFF_W2T);
    float* c1   = (float*)(ws + OFF_C1);
    float* b2f  = (float*)(ws + OFF_B2F);
    for (int i = t; i < Hh * Cc; i += 256) {
      int h = i >> 8, c = i & 255;
      float wa = w1[h * 2 * Cc + c];
      float wb = w1[h * 2 * Cc + Cc + c];
      w1as[i] = a1[h] * wa;
      w1ds[i] = a1[h] * (wb - wa);
      w2t[i] = a2c[c] * w2[c * Hh + h];   // i = h*256 + c
    }
    if (t < Hh) c1[t] = b1[t] - a1[t] * m1[t];
    if (t < Cc) b2f[t] = b2[t] - a2c[t] * m2[t];
  } else {
    // pack xyz -> float4; kv.w = |k|^2, q.w = |q|^2 + 1 (positivity bias: dist >= ~1 > 0
    // so positive-f64 value order == bit order; required by OR-packed keys)
    float4* kvp = (float4*)(ws + OFF_KVP);
    float4* qp  = (float4*)(ws + OFF_QP);
    for (int i = 0; i < 2; ++i) {
      int g = (blockIdx.x - 1) * 512 + i * 256 + t;  // 0..65535
      if (g < Bz * NKV) {
        const float* src = kxyz + (size_t)g * 3;
        float4 v; v.x = src[0]; v.y = src[1]; v.z = src[2];
        v.w = fmaf(v.x, v.x, fmaf(v.y, v.y, v.z * v.z));
        kvp[g] = v;
      } else {
        int g2i = g - Bz * NKV;
        const float* src = qxyz + (size_t)g2i * 3;
        float4 v; v.x = src[0]; v.y = src[1]; v.z = src[2];
        v.w = fmaf(v.x, v.x, fmaf(v.y, v.y, v.z * v.z)) + 1.0f;
        qp[g2i] = v;
      }
    }
  }
}

// ------------- kernel 1: per-slice EXACT top-16, OR-packed f64 (dist,idx) keys -------------
// key = bits((double)dist_f32) | idx. (double)dq has 29 zero low-mantissa bits; idx < 4096
// fits in 12. Distinct f32 dists differ by >= 2^29 mantissa units, so f64 VALUE order ==
// (fp32 dist, idx) lexicographic == jax top_k tie semantics (dist >= 1 via q.w bias =>
// positive => value order == bit order). The index (ib+J) is WAVE-UNIFORM (all lanes
// process the same key) -> folds to a scalar OR; no per-lane id registers.
// NOTE: fusing this with k_feat (round 1) regressed — I$/LDS footprint contention; keep separate.
template <int SLt>
__global__ __launch_bounds__(256) void k_sel(
    const char* __restrict__ ws_c, double* __restrict__ pd) {
  constexpr int NSLt = NKV / SLt;
  __shared__ float4 lk[SLt];
  int t = threadIdx.x;
  int qt = blockIdx.x, s = blockIdx.y, b = blockIdx.z;
  const float4* kvp = (const float4*)(ws_c + OFF_KVP) + (size_t)b * NKV + s * SLt;
  const float4* qp = (const float4*)(ws_c + OFF_QP);
#pragma unroll
  for (int i = 0; i < SLt / 256; ++i) lk[i * 256 + t] = kvp[i * 256 + t];
  int q = qt * 256 + t;
  float4 qv = qp[(size_t)b * NQ + q];
  float qx2 = -2.0f * qv.x, qy2 = -2.0f * qv.y, qz2 = -2.0f * qv.z, qw = qv.w;
  __syncthreads();
  int gbase = s * SLt;
  double b0, b1, b2, b3, b4, b5, b6, b7, b8, b9, b10, b11, b12, b13, b14, b15;
#define MK(J) { float4 kv = lk[o + J]; \
  float dq = fmaf(qx2, kv.x, fmaf(qy2, kv.y, fmaf(qz2, kv.z, kv.w + qw))); \
  c##J = __longlong_as_double(__double_as_longlong((double)dq) | (long long)(ib + J)); }
  {  // first 16 keys: sort straight into b (no sentinel merge)
    int o = 0, ib = gbase;
    double c0, c1, c2, c3, c4, c5, c6, c7, c8, c9, c10, c11, c12, c13, c14, c15;
    MK(0) MK(1) MK(2) MK(3) MK(4) MK(5) MK(6) MK(7)
    MK(8) MK(9) MK(10) MK(11) MK(12) MK(13) MK(14) MK(15)
    SORTC16
    b0 = c0; b1 = c1; b2 = c2; b3 = c3; b4 = c4; b5 = c5; b6 = c6; b7 = c7;
    b8 = c8; b9 = c9; b10 = c10; b11 = c11; b12 = c12; b13 = c13; b14 = c14; b15 = c15;
  }
#pragma unroll 2
  for (int blk = 1; blk < SLt / 16; ++blk) {
    int o = blk * 16;
    int ib = gbase + o;
    double c0, c1, c2, c3, c4, c5, c6, c7, c8, c9, c10, c11, c12, c13, c14, c15;
    MK(0) MK(1) MK(2) MK(3) MK(4) MK(5) MK(6) MK(7)
    MK(8) MK(9) MK(10) MK(11) MK(12) MK(13) MK(14) MK(15)
    SORTC16
    MERGE16
  }
#undef MK
  double* ob = pd + (((size_t)b * NQ + q) * NSLt + s) * KNN;
  ob[0] = b0; ob[1] = b1; ob[2] = b2; ob[3] = b3;
  ob[4] = b4; ob[5] = b5; ob[6] = b6; ob[7] = b7;
  ob[8] = b8; ob[9] = b9; ob[10] = b10; ob[11] = b11;
  ob[12] = b12; ob[13] = b13; ob[14] = b14; ob[15] = b15;
}

// ------------- kernel 2: kvs = (a1*w1a)·kv_feat ; qadd = (a1*w1d)·q_feat + c1 -------------
__global__ __launch_bounds__(256) void k_feat(
    const float* __restrict__ kvf, const float* __restrict__ qf,
    const char* __restrict__ ws_c, char* __restrict__ ws_o) {
  __shared__ __align__(16) float fs[64][68];
  __shared__ __align__(16) float wsh[32][68];
  int t = threadIdx.x;
  int hh = t & 15, rr = t >> 4;
  int b = blockIdx.y, m0 = blockIdx.x * 64, mode = blockIdx.z;
  const float* in = mode ? qf : kvf;
  const float* w = (const float*)(ws_c + (mode ? OFF_W1DS : OFF_W1AS));
  const float* c1 = (const float*)(ws_c + OFF_C1);
  float* out = (float*)(ws_o + (mode ? OFF_QADD : OFF_KVS));
  const float* inb = in + ((size_t)b * NKV + m0) * Cc;
  float acc[2][4] = {{0.f, 0.f, 0.f, 0.f}, {0.f, 0.f, 0.f, 0.f}};
  for (int cc = 0; cc < 4; ++cc) {
    __syncthreads();
#pragma unroll
    for (int i = 0; i < 4; ++i) {  // stage 64x64 feat tile
      int l = i * 256 + t, row = l >> 4, c4 = l & 15;
      *(float4*)&fs[row][c4 * 4] = *(const float4*)(inb + (size_t)row * Cc + cc * 64 + c4 * 4);
    }
#pragma unroll
    for (int i = 0; i < 2; ++i) {  // stage 32x64 weight tile
      int l = i * 256 + t, row = l >> 4, c4 = l & 15;
      *(float4*)&wsh[row][c4 * 4] = *(const float4*)(w + (size_t)row * Cc + cc * 64 + c4 * 4);
    }
    __syncthreads();
#pragma unroll
    for (int c4 = 0; c4 < 16; ++c4) {
      float4 w0 = *(float4*)&wsh[hh][c4 * 4];
      float4 w1v = *(float4*)&wsh[hh + 16][c4 * 4];
#pragma unroll
      for (int j = 0; j < 4; ++j) {
        float4 f = *(float4*)&fs[rr + j * 16][c4 * 4];
        acc[0][j] = fmaf(w0.x, f.x, fmaf(w0.y, f.y, fmaf(w0.z, f.z, fmaf(w0.w, f.w, acc[0][j]))));
        acc[1][j] = fmaf(w1v.x, f.x, fmaf(w1v.y, f.y, fmaf(w1v.z, f.z, fmaf(w1v.w, f.w, acc[1][j]))));
      }
    }
  }
  float add0 = mode ? c1[hh] : 0.f;
  float add1 = mode ? c1[hh + 16] : 0.f;
  float* ob = out + ((size_t)b * NKV + m0) * Hh;
#pragma unroll
  for (int j = 0; j < 4; ++j) {
    ob[(rr + j * 16) * Hh + hh] = acc[0][j] + add0;
    ob[(rr + j * 16) * Hh + hh + 16] = acc[1][j] + add1;
  }
}

// ------------- kernel 3 (fused tail): merge lists -> gather+maxpool+leaky -> matvec+BN2+leaky -------------
// block = 256 threads, 64 queries. Phases: (1a) 2 threads/q merge half-lists; (1b) 1 thread/q final
// merge -> sidx; (2) 4 lanes/q gather kvs rows + maxpool + qadd + leaky -> xs (transposed);
// (3) 64 q x 4 cb-waves: y = leaky(w2t·x + b2f).
template <int NSLt>
__global__ __launch_bounds__(256) void k_tail(
    const double* __restrict__ pd, const char* __restrict__ ws_c,
    float* __restrict__ out) {
  __shared__ double mg[64][2][KNN];   // 16 KB
  __shared__ int sidx[64 * 17];       // 4.25 KB (stride-17 pad)
  __shared__ float xs[Hh * 64];       // 8 KB, transposed: xs[h][q]
  int t = threadIdx.x;
  int b = blockIdx.y, q0 = blockIdx.x * 64;

  // ---- phase 1a ----
  if (t < 128) {
    int q = t >> 1, p = t & 1;
    constexpr int half = NSLt / 2;
    const double* L = pd + (((size_t)b * NQ + q0 + q) * NSLt + (size_t)p * half) * KNN;
    double b0 = L[0], b1 = L[1], b2 = L[2], b3 = L[3], b4 = L[4], b5 = L[5], b6 = L[6], b7 = L[7];
    double b8 = L[8], b9 = L[9], b10 = L[10], b11 = L[11], b12 = L[12], b13 = L[13], b14 = L[14], b15 = L[15];
#pragma unroll
    for (int s = 1; s < half; ++s) {
      const double* C = L + (size_t)s * KNN;
      double c0 = C[0], c1 = C[1], c2 = C[2], c3 = C[3], c4 = C[4], c5 = C[5], c6 = C[6], c7 = C[7];
      double c8 = C[8], c9 = C[9], c10 = C[10], c11 = C[11], c12 = C[12], c13 = C[13], c14 = C[14], c15 = C[15];
      MERGE16
    }
    double* m = &mg[q][p][0];
    m[0] = b0; m[1] = b1; m[2] = b2; m[3] = b3; m[4] = b4; m[5] = b5; m[6] = b6; m[7] = b7;
    m[8] = b8; m[9] = b9; m[10] = b10; m[11] = b11; m[12] = b12; m[13] = b13; m[14] = b14; m[15] = b15;
  }
  __syncthreads();
  // ---- phase 1b ----
  if (t < 64) {
    const double* A = &mg[t][0][0];
    const double* C2 = &mg[t][1][0];
    double b0 = A[0], b1 = A[1], b2 = A[2], b3 = A[3], b4 = A[4], b5 = A[5], b6 = A[6], b7 = A[7];
    double b8 = A[8], b9 = A[9], b10 = A[10], b11 = A[11], b12 = A[12], b13 = A[13], b14 = A[14], b15 = A[15];
    double c0 = C2[0], c1 = C2[1], c2 = C2[2], c3 = C2[3], c4 = C2[4], c5 = C2[5], c6 = C2[6], c7 = C2[7];
    double c8 = C2[8], c9 = C2[9], c10 = C2[10], c11 = C2[11], c12 = C2[12], c13 = C2[13], c14 = C2[14], c15 = C2[15];
    MERGE16
    // OR-packed keys: idx lives in the low 12 mantissa BITS -> extract via bit-cast
    int* si = &sidx[t * 17];
    si[0] = (int)(__double_as_longlong(b0) & 4095);
    si[1] = (int)(__double_as_longlong(b1) & 4095);
    si[2] = (int)(__double_as_longlong(b2) & 4095);
    si[3] = (int)(__double_as_longlong(b3) & 4095);
    si[4] = (int)(__double_as_longlong(b4) & 4095);
    si[5] = (int)(__double_as_longlong(b5) & 4095);
    si[6] = (int)(__double_as_longlong(b6) & 4095);
    si[7] = (int)(__double_as_longlong(b7) & 4095);
    si[8] = (int)(__double_as_longlong(b8) & 4095);
    si[9] = (int)(__double_as_longlong(b9) & 4095);
    si[10] = (int)(__double_as_longlong(b10) & 4095);
    si[11] = (int)(__double_as_longlong(b11) & 4095);
    si[12] = (int)(__double_as_longlong(b12) & 4095);
    si[13] = (int)(__double_as_longlong(b13) & 4095);
    si[14] = (int)(__double_as_longlong(b14) & 4095);
    si[15] = (int)(__double_as_longlong(b15) & 4095);
  }
  __syncthreads();
  // ---- phase 2: gather + maxpool + qadd + leaky -> xs (transposed) ----
  {
    int q = t >> 2, l = t & 3;
    const float4* kvs = (const float4*)(ws_c + OFF_KVS) + (size_t)b * NKV * 8 + l * 2;
    float4 p0 = make_float4(-3.4e38f, -3.4e38f, -3.4e38f, -3.4e38f);
    float4 p1 = p0;
#pragma unroll
    for (int n = 0; n < KNN; ++n) {
      int m = sidx[q * 17 + n];
      const float4* row = kvs + (size_t)m * 8;
      float4 v0 = row[0], v1 = row[1];
      p0.x = fmaxf(p0.x, v0.x); p0.y = fmaxf(p0.y, v0.y); p0.z = fmaxf(p0.z, v0.z); p0.w = fmaxf(p0.w, v0.w);
      p1.x = fmaxf(p1.x, v1.x); p1.y = fmaxf(p1.y, v1.y); p1.z = fmaxf(p1.z, v1.z); p1.w = fmaxf(p1.w, v1.w);
    }
    const float4* qa = (const float4*)(ws_c + OFF_QADD) + ((size_t)b * NQ + q0 + q) * 8 + l * 2;
    float4 a0 = qa[0], a1 = qa[1];
    int h0 = 8 * l;
    xs[(h0 + 0) * 64 + q] = leaky(p0.x + a0.x);
    xs[(h0 + 1) * 64 + q] = leaky(p0.y + a0.y);
    xs[(h0 + 2) * 64 + q] = leaky(p0.z + a0.z);
    xs[(h0 + 3) * 64 + q] = leaky(p0.w + a0.w);
    xs[(h0 + 4) * 64 + q] = leaky(p1.x + a1.x);
    xs[(h0 + 5) * 64 + q] = leaky(p1.y + a1.y);
    xs[(h0 + 6) * 64 + q] = leaky(p1.z + a1.z);
    xs[(h0 + 7) * 64 + q] = leaky(p1.w + a1.w);
  }
  __syncthreads();
  // ---- phase 3: y = leaky(w2t · x + b2f) ----
  {
    int ql = t & 63, cb = t >> 6;  // cb wave-uniform -> w2t loads become scalar
    const float* w2t = (const float*)(ws_c + OFF_W2T);
    const float* b2f = (const float*)(ws_c + OFF_B2F);
    float xv[Hh];
#pragma unroll
    for (int h = 0; h < Hh; ++h) xv[h] = xs[h * 64 + ql];
    float4 acc[16];
#pragma unroll
    for (int c4 = 0; c4 < 16; ++c4) acc[c4] = make_float4(0.f, 0.f, 0.f, 0.f);
#pragma unroll
    for (int h = 0; h < Hh; ++h) {
      float xh = xv[h];
      const float4* wrow = (const float4*)(w2t + (size_t)h * Cc + cb * 64);
#pragma unroll
      for (int c4 = 0; c4 < 16; ++c4) {
        float4 w = wrow[c4];
        acc[c4].x = fmaf(xh, w.x, acc[c4].x);
        acc[c4].y = fmaf(xh, w.y, acc[c4].y);
        acc[c4].z = fmaf(xh, w.z, acc[c4].z);
        acc[c4].w = fmaf(xh, w.w, acc[c4].w);
      }
    }
    float* o = out + ((size_t)b * NQ + q0 + ql) * Cc + cb * 64;
    const float4* bb = (const float4*)(b2f + cb * 64);
#pragma unroll
    for (int c4 = 0; c4 < 16; ++c4) {
      float4 bv = bb[c4];
      float4 r;
      r.x = leaky(acc[c4].x + bv.x); r.y = leaky(acc[c4].y + bv.y);
      r.z = leaky(acc[c4].z + bv.z); r.w = leaky(acc[c4].w + bv.w);
      *(float4*)(o + c4 * 4) = r;
    }
  }
}

extern "C" void kernel_launch(void* const* d_in, const int* in_sizes, int n_in,
                              void* d_out, int out_size, void* d_ws, size_t ws_size,
                              hipStream_t stream) {
  const float* qf   = (const float*)d_in[0];
  const float* qxyz = (const float*)d_in[1];
  const float* kvf  = (const float*)d_in[2];
  const float* kxyz = (const float*)d_in[3];
  const float* w1 = (const float*)d_in[4];
  const float* g1 = (const float*)d_in[5];
  const float* b1 = (const float*)d_in[6];
  const float* m1 = (const float*)d_in[7];
  const float* v1 = (const float*)d_in[8];
  const float* w2 = (const float*)d_in[9];
  const float* g2 = (const float*)d_in[10];
  const float* b2 = (const float*)d_in[11];
  const float* m2 = (const float*)d_in[12];
  const float* v2 = (const float*)d_in[13];
  char* ws = (char*)d_ws;
  double* pd = (double*)(ws + OFF_PD);

  // pd needs Bz*NQ*NSL*16*8 bytes beyond OFF_PD: NSL=16 -> ~76 MB, NSL=8 -> ~42.5 MB.
  size_t need16 = (size_t)OFF_PD + (size_t)Bz * NQ * 16 * KNN * sizeof(double);
  size_t need8  = (size_t)OFF_PD + (size_t)Bz * NQ * 8 * KNN * sizeof(double);

  k_prep<<<129, 256, 0, stream>>>(qxyz, kxyz, w1, g1, b1, m1, v1, w2, g2, b2, m2, v2, ws);
  if (ws_size >= need16) {
    // 2048 sel blocks = 8/CU (LDS 4 KB) -> better VALU filling for the f64 sort
    k_sel<256><<<dim3(NQ / 256, 16, Bz), 256, 0, stream>>>(ws, pd);
    k_feat<<<dim3(64, Bz, 2), 256, 0, stream>>>(kvf, qf, ws, ws);
    k_tail<16><<<dim3(NQ / 64, Bz), 256, 0, stream>>>(pd, ws, (float*)d_out);
  } else if (ws_size >= need8) {
    k_sel<512><<<dim3(NQ / 256, 8, Bz), 256, 0, stream>>>(ws, pd);
    k_feat<<<dim3(64, Bz, 2), 256, 0, stream>>>(kvf, qf, ws, ws);
    k_tail<8><<<dim3(NQ / 64, Bz), 256, 0, stream>>>(pd, ws, (float*)d_out);
  } else {
    k_sel<1024><<<dim3(NQ / 256, 4, Bz), 256, 0, stream>>>(ws, pd);
    k_feat<<<dim3(64, Bz, 2), 256, 0, stream>>>(kvf, qf, ws, ws);
    k_tail<4><<<dim3(NQ / 64, Bz), 256, 0, stream>>>(pd, ws, (float*)d_out);
  }
}

// Round 3
// 291.275 us; speedup vs baseline: 1.1102x; 1.0255x over previous
//
#include <hip/hip_runtime.h>
#include <math.h>

#define Bz 8
#define NQ 4096
#define NKV 4096
#define Cc 256
#define KNN 16
#define Hh 32
#define EPSf 1e-5f
#define SLOPEf 0.2f

typedef unsigned long long u64t;
typedef unsigned int u32t;

// ---- workspace layout (bytes) ----
#define OFF_W1AS 0u                       // 32*256 f32 (alpha1-folded w1a)
#define OFF_W1DS (OFF_W1AS + 32768u)      // 32*256 f32 (alpha1-folded (w1b-w1a))
#define OFF_W2T  (OFF_W1DS + 32768u)      // 32*256 f32 w2t[h][c] = alpha2[c]*w2[c][h]
#define OFF_C1   (OFF_W2T + 32768u)       // 32 f32: b1 - alpha1*m1
#define OFF_B2F  (OFF_C1 + 1024u)         // 256 f32: b2 - alpha2*m2
#define OFF_KVP  (OFF_B2F + 2048u)        // 8*4096 float4 kv xyz (w = |k|^2)
#define OFF_QP   (OFF_KVP + 524288u)      // 8*4096 float4 q xyz (w = |q|^2 + 1)
#define OFF_KVS  (OFF_QP + 524288u)       // 8*4096*32 f32
#define OFF_QADD (OFF_KVS + 4194304u)     // 8*4096*32 f32
#define OFF_PD   (OFF_QADD + 4194304u)    // 8*4096*NSL*16 f64 per-slice sorted keys

__device__ __forceinline__ float leaky(float x) { return fmaxf(x, SLOPEf * x); }

// f64 comparators: CAS = v_min_f64 + v_max_f64 (2 instrs); MN2 = v_min_f64 (1)
#define CASD(A, B) { double lo_ = fmin(A, B); double hi_ = fmax(A, B); (A) = lo_; (B) = hi_; }
#define MND(A, B)  { (A) = fmin(A, B); }

// Batcher odd-even mergesort, 16 elements, 63 comparators (c0..c15 ascending)
#define SORTC16 \
  CASD(c0,c1) CASD(c2,c3) CASD(c4,c5) CASD(c6,c7) CASD(c8,c9) CASD(c10,c11) CASD(c12,c13) CASD(c14,c15) \
  CASD(c0,c2) CASD(c4,c6) CASD(c8,c10) CASD(c12,c14) CASD(c1,c3) CASD(c5,c7) CASD(c9,c11) CASD(c13,c15) \
  CASD(c1,c2) CASD(c5,c6) CASD(c9,c10) CASD(c13,c14) \
  CASD(c0,c4) CASD(c8,c12) CASD(c1,c5) CASD(c9,c13) CASD(c2,c6) CASD(c10,c14) CASD(c3,c7) CASD(c11,c15) \
  CASD(c2,c4) CASD(c10,c12) CASD(c3,c5) CASD(c11,c13) \
  CASD(c1,c2) CASD(c3,c4) CASD(c5,c6) CASD(c9,c10) CASD(c11,c12) CASD(c13,c14) \
  CASD(c0,c8) CASD(c1,c9) CASD(c2,c10) CASD(c3,c11) CASD(c4,c12) CASD(c5,c13) CASD(c6,c14) CASD(c7,c15) \
  CASD(c4,c8) CASD(c5,c9) CASD(c6,c10) CASD(c7,c11) \
  CASD(c2,c4) CASD(c3,c5) CASD(c6,c8) CASD(c7,c9) CASD(c10,c12) CASD(c11,c13) \
  CASD(c1,c2) CASD(c3,c4) CASD(c5,c6) CASD(c7,c8) CASD(c9,c10) CASD(c11,c12) CASD(c13,c14)

// keep-lowest-16 of sorted b (asc) U sorted c (asc): reversed pairwise min, bitonic clean
#define MERGE16 \
  MND(b0,c15) MND(b1,c14) MND(b2,c13) MND(b3,c12) MND(b4,c11) MND(b5,c10) MND(b6,c9) MND(b7,c8) \
  MND(b8,c7) MND(b9,c6) MND(b10,c5) MND(b11,c4) MND(b12,c3) MND(b13,c2) MND(b14,c1) MND(b15,c0) \
  CASD(b0,b8) CASD(b1,b9) CASD(b2,b10) CASD(b3,b11) CASD(b4,b12) CASD(b5,b13) CASD(b6,b14) CASD(b7,b15) \
  CASD(b0,b4) CASD(b1,b5) CASD(b2,b6) CASD(b3,b7) CASD(b8,b12) CASD(b9,b13) CASD(b10,b14) CASD(b11,b15) \
  CASD(b0,b2) CASD(b1,b3) CASD(b4,b6) CASD(b5,b7) CASD(b8,b10) CASD(b9,b11) CASD(b12,b14) CASD(b13,b15) \
  CASD(b0,b1) CASD(b2,b3) CASD(b4,b5) CASD(b6,b7) CASD(b8,b9) CASD(b10,b11) CASD(b12,b13) CASD(b14,b15)

#define LOADB16(P) \
  b0 = (P)[0]; b1 = (P)[1]; b2 = (P)[2]; b3 = (P)[3]; b4 = (P)[4]; b5 = (P)[5]; b6 = (P)[6]; b7 = (P)[7]; \
  b8 = (P)[8]; b9 = (P)[9]; b10 = (P)[10]; b11 = (P)[11]; b12 = (P)[12]; b13 = (P)[13]; b14 = (P)[14]; b15 = (P)[15];
#define LOADC16(P) \
  c0 = (P)[0]; c1 = (P)[1]; c2 = (P)[2]; c3 = (P)[3]; c4 = (P)[4]; c5 = (P)[5]; c6 = (P)[6]; c7 = (P)[7]; \
  c8 = (P)[8]; c9 = (P)[9]; c10 = (P)[10]; c11 = (P)[11]; c12 = (P)[12]; c13 = (P)[13]; c14 = (P)[14]; c15 = (P)[15];
#define STOREB16(P) \
  (P)[0] = b0; (P)[1] = b1; (P)[2] = b2; (P)[3] = b3; (P)[4] = b4; (P)[5] = b5; (P)[6] = b6; (P)[7] = b7; \
  (P)[8] = b8; (P)[9] = b9; (P)[10] = b10; (P)[11] = b11; (P)[12] = b12; (P)[13] = b13; (P)[14] = b14; (P)[15] = b15;

// ---------------- kernel 0: fold weights + pack xyz as float4 ----------------
__global__ __launch_bounds__(256) void k_prep(
    const float* __restrict__ qxyz, const float* __restrict__ kxyz,
    const float* __restrict__ w1, const float* __restrict__ g1,
    const float* __restrict__ b1, const float* __restrict__ m1,
    const float* __restrict__ v1, const float* __restrict__ w2,
    const float* __restrict__ g2, const float* __restrict__ b2,
    const float* __restrict__ m2, const float* __restrict__ v2,
    char* __restrict__ ws) {
  int t = threadIdx.x;
  if (blockIdx.x == 0) {
    __shared__ float a1[Hh], a2c[Cc];
    if (t < Hh) a1[t] = g1[t] / sqrtf(v1[t] + EPSf);
    if (t < Cc) a2c[t] = g2[t] / sqrtf(v2[t] + EPSf);
    __syncthreads();
    float* w1as = (float*)(ws + OFF_W1AS);
    float* w1ds = (float*)(ws + OFF_W1DS);
    float* w2t  = (float*)(ws + OFF_W2T);
    float* c1   = (float*)(ws + OFF_C1);
    float* b2f  = (float*)(ws + OFF_B2F);
    for (int i = t; i < Hh * Cc; i += 256) {
      int h = i >> 8, c = i & 255;
      float wa = w1[h * 2 * Cc + c];
      float wb = w1[h * 2 * Cc + Cc + c];
      w1as[i] = a1[h] * wa;
      w1ds[i] = a1[h] * (wb - wa);
      w2t[i] = a2c[c] * w2[c * Hh + h];   // i = h*256 + c
    }
    if (t < Hh) c1[t] = b1[t] - a1[t] * m1[t];
    if (t < Cc) b2f[t] = b2[t] - a2c[t] * m2[t];
  } else {
    // pack xyz -> float4; kv.w = |k|^2, q.w = |q|^2 + 1 (positivity bias: dist >= ~1 > 0
    // so positive-f64 value order == bit order; required by OR-packed keys)
    float4* kvp = (float4*)(ws + OFF_KVP);
    float4* qp  = (float4*)(ws + OFF_QP);
    for (int i = 0; i < 2; ++i) {
      int g = (blockIdx.x - 1) * 512 + i * 256 + t;  // 0..65535
      if (g < Bz * NKV) {
        const float* src = kxyz + (size_t)g * 3;
        float4 v; v.x = src[0]; v.y = src[1]; v.z = src[2];
        v.w = fmaf(v.x, v.x, fmaf(v.y, v.y, v.z * v.z));
        kvp[g] = v;
      } else {
        int g2i = g - Bz * NKV;
        const float* src = qxyz + (size_t)g2i * 3;
        float4 v; v.x = src[0]; v.y = src[1]; v.z = src[2];
        v.w = fmaf(v.x, v.x, fmaf(v.y, v.y, v.z * v.z)) + 1.0f;
        qp[g2i] = v;
      }
    }
  }
}

// ------------- kernel 1: per-slice EXACT top-16, OR-packed f64 (dist,idx) keys -------------
// key = bits((double)dist_f32) | idx. (double)dq has 29 zero low-mantissa bits; idx < 4096
// fits in 12. Distinct f32 dists differ by >= 2^29 mantissa units, so f64 VALUE order ==
// (fp32 dist, idx) lexicographic == jax top_k tie semantics (dist >= 1 via q.w bias =>
// positive => value order == bit order). The index (ib+J) is WAVE-UNIFORM (all lanes
// process the same key) -> folds to a scalar OR; no per-lane id registers.
// NOTE: fusing this with k_feat (round 1) regressed — I$/LDS footprint contention.
// NOTE: NSL=16 (round 2) regressed — doubles pd HBM traffic + tail merge work.
template <int SLt>
__global__ __launch_bounds__(256) void k_sel(
    const char* __restrict__ ws_c, double* __restrict__ pd) {
  constexpr int NSLt = NKV / SLt;
  __shared__ float4 lk[SLt];
  int t = threadIdx.x;
  int qt = blockIdx.x, s = blockIdx.y, b = blockIdx.z;
  const float4* kvp = (const float4*)(ws_c + OFF_KVP) + (size_t)b * NKV + s * SLt;
  const float4* qp = (const float4*)(ws_c + OFF_QP);
#pragma unroll
  for (int i = 0; i < SLt / 256; ++i) lk[i * 256 + t] = kvp[i * 256 + t];
  int q = qt * 256 + t;
  float4 qv = qp[(size_t)b * NQ + q];
  float qx2 = -2.0f * qv.x, qy2 = -2.0f * qv.y, qz2 = -2.0f * qv.z, qw = qv.w;
  __syncthreads();
  int gbase = s * SLt;
  double b0, b1, b2, b3, b4, b5, b6, b7, b8, b9, b10, b11, b12, b13, b14, b15;
#define MK(J) { float4 kv = lk[o + J]; \
  float dq = fmaf(qx2, kv.x, fmaf(qy2, kv.y, fmaf(qz2, kv.z, kv.w + qw))); \
  c##J = __longlong_as_double(__double_as_longlong((double)dq) | (long long)(ib + J)); }
  {  // first 16 keys: sort straight into b (no sentinel merge)
    int o = 0, ib = gbase;
    double c0, c1, c2, c3, c4, c5, c6, c7, c8, c9, c10, c11, c12, c13, c14, c15;
    MK(0) MK(1) MK(2) MK(3) MK(4) MK(5) MK(6) MK(7)
    MK(8) MK(9) MK(10) MK(11) MK(12) MK(13) MK(14) MK(15)
    SORTC16
    b0 = c0; b1 = c1; b2 = c2; b3 = c3; b4 = c4; b5 = c5; b6 = c6; b7 = c7;
    b8 = c8; b9 = c9; b10 = c10; b11 = c11; b12 = c12; b13 = c13; b14 = c14; b15 = c15;
  }
#pragma unroll 2
  for (int blk = 1; blk < SLt / 16; ++blk) {
    int o = blk * 16;
    int ib = gbase + o;
    double c0, c1, c2, c3, c4, c5, c6, c7, c8, c9, c10, c11, c12, c13, c14, c15;
    MK(0) MK(1) MK(2) MK(3) MK(4) MK(5) MK(6) MK(7)
    MK(8) MK(9) MK(10) MK(11) MK(12) MK(13) MK(14) MK(15)
    SORTC16
    MERGE16
  }
#undef MK
  double* ob = pd + (((size_t)b * NQ + q) * NSLt + s) * KNN;
  ob[0] = b0; ob[1] = b1; ob[2] = b2; ob[3] = b3;
  ob[4] = b4; ob[5] = b5; ob[6] = b6; ob[7] = b7;
  ob[8] = b8; ob[9] = b9; ob[10] = b10; ob[11] = b11;
  ob[12] = b12; ob[13] = b13; ob[14] = b14; ob[15] = b15;
}

// ------------- kernel 2: kvs = (a1*w1a)·kv_feat ; qadd = (a1*w1d)·q_feat + c1 -------------
__global__ __launch_bounds__(256) void k_feat(
    const float* __restrict__ kvf, const float* __restrict__ qf,
    const char* __restrict__ ws_c, char* __restrict__ ws_o) {
  __shared__ __align__(16) float fs[64][68];
  __shared__ __align__(16) float wsh[32][68];
  int t = threadIdx.x;
  int hh = t & 15, rr = t >> 4;
  int b = blockIdx.y, m0 = blockIdx.x * 64, mode = blockIdx.z;
  const float* in = mode ? qf : kvf;
  const float* w = (const float*)(ws_c + (mode ? OFF_W1DS : OFF_W1AS));
  const float* c1 = (const float*)(ws_c + OFF_C1);
  float* out = (float*)(ws_o + (mode ? OFF_QADD : OFF_KVS));
  const float* inb = in + ((size_t)b * NKV + m0) * Cc;
  float acc[2][4] = {{0.f, 0.f, 0.f, 0.f}, {0.f, 0.f, 0.f, 0.f}};
  for (int cc = 0; cc < 4; ++cc) {
    __syncthreads();
#pragma unroll
    for (int i = 0; i < 4; ++i) {  // stage 64x64 feat tile
      int l = i * 256 + t, row = l >> 4, c4 = l & 15;
      *(float4*)&fs[row][c4 * 4] = *(const float4*)(inb + (size_t)row * Cc + cc * 64 + c4 * 4);
    }
#pragma unroll
    for (int i = 0; i < 2; ++i) {  // stage 32x64 weight tile
      int l = i * 256 + t, row = l >> 4, c4 = l & 15;
      *(float4*)&wsh[row][c4 * 4] = *(const float4*)(w + (size_t)row * Cc + cc * 64 + c4 * 4);
    }
    __syncthreads();
#pragma unroll
    for (int c4 = 0; c4 < 16; ++c4) {
      float4 w0 = *(float4*)&wsh[hh][c4 * 4];
      float4 w1v = *(float4*)&wsh[hh + 16][c4 * 4];
#pragma unroll
      for (int j = 0; j < 4; ++j) {
        float4 f = *(float4*)&fs[rr + j * 16][c4 * 4];
        acc[0][j] = fmaf(w0.x, f.x, fmaf(w0.y, f.y, fmaf(w0.z, f.z, fmaf(w0.w, f.w, acc[0][j]))));
        acc[1][j] = fmaf(w1v.x, f.x, fmaf(w1v.y, f.y, fmaf(w1v.z, f.z, fmaf(w1v.w, f.w, acc[1][j]))));
      }
    }
  }
  float add0 = mode ? c1[hh] : 0.f;
  float add1 = mode ? c1[hh + 16] : 0.f;
  float* ob = out + ((size_t)b * NKV + m0) * Hh;
#pragma unroll
  for (int j = 0; j < 4; ++j) {
    ob[(rr + j * 16) * Hh + hh] = acc[0][j] + add0;
    ob[(rr + j * 16) * Hh + hh + 16] = acc[1][j] + add1;
  }
}

// ------------- kernel 3 (fused tail): parallel merge tree -> gather+maxpool+leaky -> matvec+BN2+leaky -------
// block = 256 threads, 64 queries.
// Phase 1 (NSL=8): level 1 = ALL 256 threads (4/q), each loads its TWO contiguous lists
// (one 256 B burst, all loads in flight block-wide) + 1 MERGE16 -> mg; level 2 = 128 thr
// LDS merge -> mg2; level 3 = 64 thr final merge -> sidx. Critical path: 1 global-load
// latency + 3 MERGE16s (was 4 serially-dependent load+merge rounds).
// LDS stride 17 doubles: with [..][16], the q-stride is 128 words === 0 mod 32 -> all lanes
// same bank (32-way conflict, the saturated SQ_LDS_BANK_CONFLICT of rounds 0-2).
template <int NSLt>
__global__ __launch_bounds__(256) void k_tail(
    const double* __restrict__ pd, const char* __restrict__ ws_c,
    float* __restrict__ out) {
  __shared__ double mg[64][NSLt / 2][17];            // 34 KB (NSL=8) / 17 KB (NSL=4)
  __shared__ double mg2[(NSLt == 8) ? 64 : 1][2][17];
  __shared__ int sidx[64 * 17];       // 4.25 KB (stride-17 pad)
  __shared__ float xs[Hh * 64];       // 8 KB, transposed: xs[h][q]
  int t = threadIdx.x;
  int b = blockIdx.y, q0 = blockIdx.x * 64;
  const double* base = pd + ((size_t)b * NQ + q0) * NSLt * KNN;

  double b0, b1, b2, b3, b4, b5, b6, b7, b8, b9, b10, b11, b12, b13, b14, b15;
  double c0, c1, c2, c3, c4, c5, c6, c7, c8, c9, c10, c11, c12, c13, c14, c15;

  if (NSLt == 8) {
    {  // level 1: 4 threads/q, thread p merges lists (2p, 2p+1) — contiguous 256 B
      int q = t >> 2, p = t & 3;
      const double* L = base + ((size_t)q * NSLt + 2 * p) * KNN;
      LOADB16(L)
      LOADC16(L + 16)
      MERGE16
      STOREB16(&mg[q][p][0])
    }
    __syncthreads();
    if (t < 128) {  // level 2
      int q = t >> 1, p = t & 1;
      LOADB16(&mg[q][2 * p][0])
      LOADC16(&mg[q][2 * p + 1][0])
      MERGE16
      STOREB16(&mg2[q][p][0])
    }
    __syncthreads();
  } else {  // NSLt == 4
    if (t < 128) {
      int q = t >> 1, p = t & 1;
      const double* L = base + ((size_t)q * NSLt + 2 * p) * KNN;
      LOADB16(L)
      LOADC16(L + 16)
      MERGE16
      STOREB16(&mg[q][p][0])
    }
    __syncthreads();
  }
  if (t < 64) {  // final level -> sidx
    if (NSLt == 8) {
      LOADB16(&mg2[t][0][0])
      LOADC16(&mg2[t][1][0])
    } else {
      LOADB16(&mg[t][0][0])
      LOADC16(&mg[t][1][0])
    }
    MERGE16
    // OR-packed keys: idx lives in the low 12 mantissa BITS -> extract via bit-cast
    int* si = &sidx[t * 17];
    si[0] = (int)(__double_as_longlong(b0) & 4095);
    si[1] = (int)(__double_as_longlong(b1) & 4095);
    si[2] = (int)(__double_as_longlong(b2) & 4095);
    si[3] = (int)(__double_as_longlong(b3) & 4095);
    si[4] = (int)(__double_as_longlong(b4) & 4095);
    si[5] = (int)(__double_as_longlong(b5) & 4095);
    si[6] = (int)(__double_as_longlong(b6) & 4095);
    si[7] = (int)(__double_as_longlong(b7) & 4095);
    si[8] = (int)(__double_as_longlong(b8) & 4095);
    si[9] = (int)(__double_as_longlong(b9) & 4095);
    si[10] = (int)(__double_as_longlong(b10) & 4095);
    si[11] = (int)(__double_as_longlong(b11) & 4095);
    si[12] = (int)(__double_as_longlong(b12) & 4095);
    si[13] = (int)(__double_as_longlong(b13) & 4095);
    si[14] = (int)(__double_as_longlong(b14) & 4095);
    si[15] = (int)(__double_as_longlong(b15) & 4095);
  }
  __syncthreads();
  // ---- phase 2: gather + maxpool + qadd + leaky -> xs (transposed) ----
  {
    int q = t >> 2, l = t & 3;
    const float4* kvs = (const float4*)(ws_c + OFF_KVS) + (size_t)b * NKV * 8 + l * 2;
    float4 p0 = make_float4(-3.4e38f, -3.4e38f, -3.4e38f, -3.4e38f);
    float4 p1 = p0;
#pragma unroll
    for (int n = 0; n < KNN; ++n) {
      int m = sidx[q * 17 + n];
      const float4* row = kvs + (size_t)m * 8;
      float4 v0 = row[0], v1 = row[1];
      p0.x = fmaxf(p0.x, v0.x); p0.y = fmaxf(p0.y, v0.y); p0.z = fmaxf(p0.z, v0.z); p0.w = fmaxf(p0.w, v0.w);
      p1.x = fmaxf(p1.x, v1.x); p1.y = fmaxf(p1.y, v1.y); p1.z = fmaxf(p1.z, v1.z); p1.w = fmaxf(p1.w, v1.w);
    }
    const float4* qa = (const float4*)(ws_c + OFF_QADD) + ((size_t)b * NQ + q0 + q) * 8 + l * 2;
    float4 a0 = qa[0], a1 = qa[1];
    int h0 = 8 * l;
    xs[(h0 + 0) * 64 + q] = leaky(p0.x + a0.x);
    xs[(h0 + 1) * 64 + q] = leaky(p0.y + a0.y);
    xs[(h0 + 2) * 64 + q] = leaky(p0.z + a0.z);
    xs[(h0 + 3) * 64 + q] = leaky(p0.w + a0.w);
    xs[(h0 + 4) * 64 + q] = leaky(p1.x + a1.x);
    xs[(h0 + 5) * 64 + q] = leaky(p1.y + a1.y);
    xs[(h0 + 6) * 64 + q] = leaky(p1.z + a1.z);
    xs[(h0 + 7) * 64 + q] = leaky(p1.w + a1.w);
  }
  __syncthreads();
  // ---- phase 3: y = leaky(w2t · x + b2f) ----
  {
    int ql = t & 63, cb = t >> 6;  // cb wave-uniform -> w2t loads become scalar
    const float* w2t = (const float*)(ws_c + OFF_W2T);
    const float* b2f = (const float*)(ws_c + OFF_B2F);
    float xv[Hh];
#pragma unroll
    for (int h = 0; h < Hh; ++h) xv[h] = xs[h * 64 + ql];
    float4 acc[16];
#pragma unroll
    for (int c4 = 0; c4 < 16; ++c4) acc[c4] = make_float4(0.f, 0.f, 0.f, 0.f);
#pragma unroll
    for (int h = 0; h < Hh; ++h) {
      float xh = xv[h];
      const float4* wrow = (const float4*)(w2t + (size_t)h * Cc + cb * 64);
#pragma unroll
      for (int c4 = 0; c4 < 16; ++c4) {
        float4 w = wrow[c4];
        acc[c4].x = fmaf(xh, w.x, acc[c4].x);
        acc[c4].y = fmaf(xh, w.y, acc[c4].y);
        acc[c4].z = fmaf(xh, w.z, acc[c4].z);
        acc[c4].w = fmaf(xh, w.w, acc[c4].w);
      }
    }
    float* o = out + ((size_t)b * NQ + q0 + ql) * Cc + cb * 64;
    const float4* bb = (const float4*)(b2f + cb * 64);
#pragma unroll
    for (int c4 = 0; c4 < 16; ++c4) {
      float4 bv = bb[c4];
      float4 r;
      r.x = leaky(acc[c4].x + bv.x); r.y = leaky(acc[c4].y + bv.y);
      r.z = leaky(acc[c4].z + bv.z); r.w = leaky(acc[c4].w + bv.w);
      *(float4*)(o + c4 * 4) = r;
    }
  }
}

extern "C" void kernel_launch(void* const* d_in, const int* in_sizes, int n_in,
                              void* d_out, int out_size, void* d_ws, size_t ws_size,
                              hipStream_t stream) {
  const float* qf   = (const float*)d_in[0];
  const float* qxyz = (const float*)d_in[1];
  const float* kvf  = (const float*)d_in[2];
  const float* kxyz = (const float*)d_in[3];
  const float* w1 = (const float*)d_in[4];
  const float* g1 = (const float*)d_in[5];
  const float* b1 = (const float*)d_in[6];
  const float* m1 = (const float*)d_in[7];
  const float* v1 = (const float*)d_in[8];
  const float* w2 = (const float*)d_in[9];
  const float* g2 = (const float*)d_in[10];
  const float* b2 = (const float*)d_in[11];
  const float* m2 = (const float*)d_in[12];
  const float* v2 = (const float*)d_in[13];
  char* ws = (char*)d_ws;
  double* pd = (double*)(ws + OFF_PD);

  // NSL=8 needs OFF_PD + 8*4096*8*16*8 = ~42.5 MB of ws; fall back to NSL=4 otherwise.
  size_t need8 = (size_t)OFF_PD + (size_t)Bz * NQ * 8 * KNN * sizeof(double);
  bool big = ws_size >= need8;

  k_prep<<<129, 256, 0, stream>>>(qxyz, kxyz, w1, g1, b1, m1, v1, w2, g2, b2, m2, v2, ws);
  if (big) {
    k_sel<512><<<dim3(NQ / 256, 8, Bz), 256, 0, stream>>>(ws, pd);
    k_feat<<<dim3(64, Bz, 2), 256, 0, stream>>>(kvf, qf, ws, ws);
    k_tail<8><<<dim3(NQ / 64, Bz), 256, 0, stream>>>(pd, ws, (float*)d_out);
  } else {
    k_sel<1024><<<dim3(NQ / 256, 4, Bz), 256, 0, stream>>>(ws, pd);
    k_feat<<<dim3(64, Bz, 2), 256, 0, stream>>>(kvf, qf, ws, ws);
    k_tail<4><<<dim3(NQ / 64, Bz), 256, 0, stream>>>(pd, ws, (float*)d_out);
  }
}

// Round 4
// 289.773 us; speedup vs baseline: 1.1159x; 1.0052x over previous
//
#include <hip/hip_runtime.h>
#include <math.h>

#define Bz 8
#define NQ 4096
#define NKV 4096
#define Cc 256
#define KNN 16
#define Hh 32
#define EPSf 1e-5f
#define SLOPEf 0.2f

typedef unsigned long long u64t;
typedef unsigned int u32t;

// ---- workspace layout (bytes) ----
#define OFF_W1AS 0u                       // 32*256 f32 (alpha1-folded w1a)
#define OFF_W1DS (OFF_W1AS + 32768u)      // 32*256 f32 (alpha1-folded (w1b-w1a))
#define OFF_W2T  (OFF_W1DS + 32768u)      // 32*256 f32 w2t[h][c] = alpha2[c]*w2[c][h]
#define OFF_C1   (OFF_W2T + 32768u)       // 32 f32: b1 - alpha1*m1
#define OFF_B2F  (OFF_C1 + 1024u)         // 256 f32: b2 - alpha2*m2
#define OFF_KVP  (OFF_B2F + 2048u)        // 8*4096 float4 kv xyz (w = |k|^2)
#define OFF_QP   (OFF_KVP + 524288u)      // 8*4096 float4 q xyz (w = |q|^2 + 1)
#define OFF_KVS  (OFF_QP + 524288u)       // 8*4096*32 f32
#define OFF_QADD (OFF_KVS + 4194304u)     // 8*4096*32 f32
#define OFF_PD   (OFF_QADD + 4194304u)    // 8*4096*NSL*16 f64 per-slice sorted keys

__device__ __forceinline__ float leaky(float x) { return fmaxf(x, SLOPEf * x); }

// f64 comparators: CAS = v_min_f64 + v_max_f64 (2 instrs); MN2 = v_min_f64 (1)
#define CASD(A, B) { double lo_ = fmin(A, B); double hi_ = fmax(A, B); (A) = lo_; (B) = hi_; }
#define MND(A, B)  { (A) = fmin(A, B); }

// Batcher odd-even mergesort, 16 elements, 63 comparators (c0..c15 ascending)
#define SORTC16 \
  CASD(c0,c1) CASD(c2,c3) CASD(c4,c5) CASD(c6,c7) CASD(c8,c9) CASD(c10,c11) CASD(c12,c13) CASD(c14,c15) \
  CASD(c0,c2) CASD(c4,c6) CASD(c8,c10) CASD(c12,c14) CASD(c1,c3) CASD(c5,c7) CASD(c9,c11) CASD(c13,c15) \
  CASD(c1,c2) CASD(c5,c6) CASD(c9,c10) CASD(c13,c14) \
  CASD(c0,c4) CASD(c8,c12) CASD(c1,c5) CASD(c9,c13) CASD(c2,c6) CASD(c10,c14) CASD(c3,c7) CASD(c11,c15) \
  CASD(c2,c4) CASD(c10,c12) CASD(c3,c5) CASD(c11,c13) \
  CASD(c1,c2) CASD(c3,c4) CASD(c5,c6) CASD(c9,c10) CASD(c11,c12) CASD(c13,c14) \
  CASD(c0,c8) CASD(c1,c9) CASD(c2,c10) CASD(c3,c11) CASD(c4,c12) CASD(c5,c13) CASD(c6,c14) CASD(c7,c15) \
  CASD(c4,c8) CASD(c5,c9) CASD(c6,c10) CASD(c7,c11) \
  CASD(c2,c4) CASD(c3,c5) CASD(c6,c8) CASD(c7,c9) CASD(c10,c12) CASD(c11,c13) \
  CASD(c1,c2) CASD(c3,c4) CASD(c5,c6) CASD(c7,c8) CASD(c9,c10) CASD(c11,c12) CASD(c13,c14)

// keep-lowest-16 of sorted b (asc) U sorted c (asc): reversed pairwise min, bitonic clean
#define MERGE16 \
  MND(b0,c15) MND(b1,c14) MND(b2,c13) MND(b3,c12) MND(b4,c11) MND(b5,c10) MND(b6,c9) MND(b7,c8) \
  MND(b8,c7) MND(b9,c6) MND(b10,c5) MND(b11,c4) MND(b12,c3) MND(b13,c2) MND(b14,c1) MND(b15,c0) \
  CASD(b0,b8) CASD(b1,b9) CASD(b2,b10) CASD(b3,b11) CASD(b4,b12) CASD(b5,b13) CASD(b6,b14) CASD(b7,b15) \
  CASD(b0,b4) CASD(b1,b5) CASD(b2,b6) CASD(b3,b7) CASD(b8,b12) CASD(b9,b13) CASD(b10,b14) CASD(b11,b15) \
  CASD(b0,b2) CASD(b1,b3) CASD(b4,b6) CASD(b5,b7) CASD(b8,b10) CASD(b9,b11) CASD(b12,b14) CASD(b13,b15) \
  CASD(b0,b1) CASD(b2,b3) CASD(b4,b5) CASD(b6,b7) CASD(b8,b9) CASD(b10,b11) CASD(b12,b13) CASD(b14,b15)

#define LOADB16(P) \
  b0 = (P)[0]; b1 = (P)[1]; b2 = (P)[2]; b3 = (P)[3]; b4 = (P)[4]; b5 = (P)[5]; b6 = (P)[6]; b7 = (P)[7]; \
  b8 = (P)[8]; b9 = (P)[9]; b10 = (P)[10]; b11 = (P)[11]; b12 = (P)[12]; b13 = (P)[13]; b14 = (P)[14]; b15 = (P)[15];
#define LOADC16(P) \
  c0 = (P)[0]; c1 = (P)[1]; c2 = (P)[2]; c3 = (P)[3]; c4 = (P)[4]; c5 = (P)[5]; c6 = (P)[6]; c7 = (P)[7]; \
  c8 = (P)[8]; c9 = (P)[9]; c10 = (P)[10]; c11 = (P)[11]; c12 = (P)[12]; c13 = (P)[13]; c14 = (P)[14]; c15 = (P)[15];
#define STOREB16(P) \
  (P)[0] = b0; (P)[1] = b1; (P)[2] = b2; (P)[3] = b3; (P)[4] = b4; (P)[5] = b5; (P)[6] = b6; (P)[7] = b7; \
  (P)[8] = b8; (P)[9] = b9; (P)[10] = b10; (P)[11] = b11; (P)[12] = b12; (P)[13] = b13; (P)[14] = b14; (P)[15] = b15;

// ---------------- kernel 0: fold weights + pack xyz as float4 ----------------
__global__ __launch_bounds__(256) void k_prep(
    const float* __restrict__ qxyz, const float* __restrict__ kxyz,
    const float* __restrict__ w1, const float* __restrict__ g1,
    const float* __restrict__ b1, const float* __restrict__ m1,
    const float* __restrict__ v1, const float* __restrict__ w2,
    const float* __restrict__ g2, const float* __restrict__ b2,
    const float* __restrict__ m2, const float* __restrict__ v2,
    char* __restrict__ ws) {
  int t = threadIdx.x;
  if (blockIdx.x == 0) {
    __shared__ float a1[Hh], a2c[Cc];
    if (t < Hh) a1[t] = g1[t] / sqrtf(v1[t] + EPSf);
    if (t < Cc) a2c[t] = g2[t] / sqrtf(v2[t] + EPSf);
    __syncthreads();
    float* w1as = (float*)(ws + OFF_W1AS);
    float* w1ds = (float*)(ws + OFF_W1DS);
    float* w2t  = (float*)(ws + OFF_W2T);
    float* c1   = (float*)(ws + OFF_C1);
    float* b2f  = (float*)(ws + OFF_B2F);
    for (int i = t; i < Hh * Cc; i += 256) {
      int h = i >> 8, c = i & 255;
      float wa = w1[h * 2 * Cc + c];
      float wb = w1[h * 2 * Cc + Cc + c];
      w1as[i] = a1[h] * wa;
      w1ds[i] = a1[h] * (wb - wa);
    }
    // w2 transpose: linear (coalesced) read, scatter write (writes are fire-and-forget)
    for (int j = t; j < Cc * Hh; j += 256) {
      int c = j >> 5, h = j & 31;
      w2t[h * Cc + c] = a2c[c] * w2[j];
    }
    if (t < Hh) c1[t] = b1[t] - a1[t] * m1[t];
    if (t < Cc) b2f[t] = b2[t] - a2c[t] * m2[t];
  } else {
    // pack xyz -> float4; kv.w = |k|^2, q.w = |q|^2 + 1 (positivity bias: dist >= ~1 > 0
    // so positive-f64 value order == bit order; required by OR-packed keys)
    float4* kvp = (float4*)(ws + OFF_KVP);
    float4* qp  = (float4*)(ws + OFF_QP);
    for (int i = 0; i < 2; ++i) {
      int g = (blockIdx.x - 1) * 512 + i * 256 + t;  // 0..65535
      if (g < Bz * NKV) {
        const float* src = kxyz + (size_t)g * 3;
        float4 v; v.x = src[0]; v.y = src[1]; v.z = src[2];
        v.w = fmaf(v.x, v.x, fmaf(v.y, v.y, v.z * v.z));
        kvp[g] = v;
      } else {
        int g2i = g - Bz * NKV;
        const float* src = qxyz + (size_t)g2i * 3;
        float4 v; v.x = src[0]; v.y = src[1]; v.z = src[2];
        v.w = fmaf(v.x, v.x, fmaf(v.y, v.y, v.z * v.z)) + 1.0f;
        qp[g2i] = v;
      }
    }
  }
}

// ------------- kernel 1: per-slice EXACT top-16, OR-packed f64 (dist,idx) keys -------------
// key = bits((double)dist_f32) | idx. (double)dq has 29 zero low-mantissa bits; idx < 4096
// fits in 12. Distinct f32 dists differ by >= 2^29 mantissa units, so f64 VALUE order ==
// (fp32 dist, idx) lexicographic == jax top_k tie semantics (dist >= 1 via q.w bias =>
// positive => value order == bit order). The index (ib+J) is WAVE-UNIFORM -> scalar OR.
// NOTE: fusing with k_feat (r1) regressed (I$/LDS contention); NSL=16 (r2) regressed
// (2x pd HBM traffic). 81% VALUBusy at the f64-sort floor; unroll 4 for inter-block ILP.
template <int SLt>
__global__ __launch_bounds__(256) void k_sel(
    const char* __restrict__ ws_c, double* __restrict__ pd) {
  constexpr int NSLt = NKV / SLt;
  __shared__ float4 lk[SLt];
  int t = threadIdx.x;
  int qt = blockIdx.x, s = blockIdx.y, b = blockIdx.z;
  const float4* kvp = (const float4*)(ws_c + OFF_KVP) + (size_t)b * NKV + s * SLt;
  const float4* qp = (const float4*)(ws_c + OFF_QP);
#pragma unroll
  for (int i = 0; i < SLt / 256; ++i) lk[i * 256 + t] = kvp[i * 256 + t];
  int q = qt * 256 + t;
  float4 qv = qp[(size_t)b * NQ + q];
  float qx2 = -2.0f * qv.x, qy2 = -2.0f * qv.y, qz2 = -2.0f * qv.z, qw = qv.w;
  __syncthreads();
  int gbase = s * SLt;
  double b0, b1, b2, b3, b4, b5, b6, b7, b8, b9, b10, b11, b12, b13, b14, b15;
#define MK(J) { float4 kv = lk[o + J]; \
  float dq = fmaf(qx2, kv.x, fmaf(qy2, kv.y, fmaf(qz2, kv.z, kv.w + qw))); \
  c##J = __longlong_as_double(__double_as_longlong((double)dq) | (long long)(ib + J)); }
  {  // first 16 keys: sort straight into b (no sentinel merge)
    int o = 0, ib = gbase;
    double c0, c1, c2, c3, c4, c5, c6, c7, c8, c9, c10, c11, c12, c13, c14, c15;
    MK(0) MK(1) MK(2) MK(3) MK(4) MK(5) MK(6) MK(7)
    MK(8) MK(9) MK(10) MK(11) MK(12) MK(13) MK(14) MK(15)
    SORTC16
    b0 = c0; b1 = c1; b2 = c2; b3 = c3; b4 = c4; b5 = c5; b6 = c6; b7 = c7;
    b8 = c8; b9 = c9; b10 = c10; b11 = c11; b12 = c12; b13 = c13; b14 = c14; b15 = c15;
  }
#pragma unroll 4
  for (int blk = 1; blk < SLt / 16; ++blk) {
    int o = blk * 16;
    int ib = gbase + o;
    double c0, c1, c2, c3, c4, c5, c6, c7, c8, c9, c10, c11, c12, c13, c14, c15;
    MK(0) MK(1) MK(2) MK(3) MK(4) MK(5) MK(6) MK(7)
    MK(8) MK(9) MK(10) MK(11) MK(12) MK(13) MK(14) MK(15)
    SORTC16
    MERGE16
  }
#undef MK
  double* ob = pd + (((size_t)b * NQ + q) * NSLt + s) * KNN;
  ob[0] = b0; ob[1] = b1; ob[2] = b2; ob[3] = b3;
  ob[4] = b4; ob[5] = b5; ob[6] = b6; ob[7] = b7;
  ob[8] = b8; ob[9] = b9; ob[10] = b10; ob[11] = b11;
  ob[12] = b12; ob[13] = b13; ob[14] = b14; ob[15] = b15;
}

// ------------- kernel 2: kvs = (a1*w1a)·kv_feat ; qadd = (a1*w1d)·q_feat + c1 -------------
// r4 restructure: 128-row tiles, acc[4h][4r] per thread -> LDS reads per fma drop
// 6/32 -> 8/64 (the 384 ds_read_b128/thread LDS-pipe floor was ~31 us at 16 waves/CU).
// fma chain order per output element is IDENTICAL to the old version (bit-exact).
__global__ __launch_bounds__(256) void k_feat(
    const float* __restrict__ kvf, const float* __restrict__ qf,
    const char* __restrict__ ws_c, char* __restrict__ ws_o) {
  __shared__ __align__(16) float fs[128][68];   // 34.8 KB
  __shared__ __align__(16) float wsh[32][68];   // 8.7 KB
  int t = threadIdx.x;
  int hh = t & 7, rr = t >> 3;                  // hh 0..7, rr 0..31
  int b = blockIdx.y, m0 = blockIdx.x * 128, mode = blockIdx.z;
  const float* in = mode ? qf : kvf;
  const float* w = (const float*)(ws_c + (mode ? OFF_W1DS : OFF_W1AS));
  const float* c1 = (const float*)(ws_c + OFF_C1);
  float* out = (float*)(ws_o + (mode ? OFF_QADD : OFF_KVS));
  const float* inb = in + ((size_t)b * NKV + m0) * Cc;
  float acc[4][4];
#pragma unroll
  for (int i = 0; i < 4; ++i)
#pragma unroll
    for (int j = 0; j < 4; ++j) acc[i][j] = 0.f;
  for (int cc = 0; cc < 4; ++cc) {
    __syncthreads();
#pragma unroll
    for (int i = 0; i < 8; ++i) {  // stage 128x64 feat tile
      int l = i * 256 + t, row = l >> 4, c4 = l & 15;
      *(float4*)&fs[row][c4 * 4] = *(const float4*)(inb + (size_t)row * Cc + cc * 64 + c4 * 4);
    }
#pragma unroll
    for (int i = 0; i < 2; ++i) {  // stage 32x64 weight tile
      int l = i * 256 + t, row = l >> 4, c4 = l & 15;
      *(float4*)&wsh[row][c4 * 4] = *(const float4*)(w + (size_t)row * Cc + cc * 64 + c4 * 4);
    }
    __syncthreads();
#pragma unroll
    for (int c4 = 0; c4 < 16; ++c4) {
      float4 wv[4], fv[4];
#pragma unroll
      for (int i = 0; i < 4; ++i) wv[i] = *(float4*)&wsh[hh + i * 8][c4 * 4];
#pragma unroll
      for (int j = 0; j < 4; ++j) fv[j] = *(float4*)&fs[rr + j * 32][c4 * 4];
#pragma unroll
      for (int i = 0; i < 4; ++i)
#pragma unroll
        for (int j = 0; j < 4; ++j)
          acc[i][j] = fmaf(wv[i].x, fv[j].x, fmaf(wv[i].y, fv[j].y,
                      fmaf(wv[i].z, fv[j].z, fmaf(wv[i].w, fv[j].w, acc[i][j]))));
    }
  }
  float* ob = out + ((size_t)b * NKV + m0) * Hh;
#pragma unroll
  for (int i = 0; i < 4; ++i) {
    float add = mode ? c1[hh + i * 8] : 0.f;
#pragma unroll
    for (int j = 0; j < 4; ++j)
      ob[(size_t)(rr + j * 32) * Hh + hh + i * 8] = acc[i][j] + add;
  }
}

// ------------- kernel 3 (fused tail): merge tree -> gather+maxpool+leaky -> matvec+BN2+leaky -------------
// r4: 32 q/block (1024 blocks = 4/CU, 2x the latency overlap of the 64-q version),
// qadd load hoisted to kernel entry, xs padded to stride 33 (stride-32 write was an
// 8-way bank conflict).
template <int NSLt>
__global__ __launch_bounds__(256) void k_tail(
    const double* __restrict__ pd, const char* __restrict__ ws_c,
    float* __restrict__ out) {
  __shared__ double mg[32][NSLt / 2][17];                 // 17.4 KB (NSL=8)
  __shared__ double mg2[(NSLt == 8) ? 32 : 1][2][17];     // 8.7 KB
  __shared__ int sidx[32 * 17];                           // 2.2 KB
  __shared__ float xs[Hh * 33];                           // 4.2 KB, xs[h][q] stride 33
  int t = threadIdx.x;
  int b = blockIdx.y, q0 = blockIdx.x * 32;

  // hoisted phase-2 operand (independent of phase 1)
  int q2 = t >> 3, l2 = t & 7;
  const float4* qa = (const float4*)(ws_c + OFF_QADD) + ((size_t)b * NQ + q0 + q2) * 8 + l2;
  float4 av = *qa;

  const double* base = pd + ((size_t)b * NQ + q0) * NSLt * KNN;
  double b0, b1, b2, b3, b4, b5, b6, b7, b8, b9, b10, b11, b12, b13, b14, b15;
  double c0, c1, c2, c3, c4, c5, c6, c7, c8, c9, c10, c11, c12, c13, c14, c15;

  if constexpr (NSLt == 8) {
    if (t < 128) {  // level 1: 4 thr/q, thread p merges lists (2p, 2p+1) — contiguous 256 B
      int q = t >> 2, p = t & 3;
      const double* L = base + ((size_t)q * NSLt + 2 * p) * KNN;
      LOADB16(L)
      LOADC16(L + 16)
      MERGE16
      STOREB16(&mg[q][p][0])
    }
    __syncthreads();
    if (t < 64) {  // level 2
      int q = t >> 1, p = t & 1;
      LOADB16(&mg[q][2 * p][0])
      LOADC16(&mg[q][2 * p + 1][0])
      MERGE16
      STOREB16(&mg2[q][p][0])
    }
    __syncthreads();
  } else {  // NSLt == 4
    if (t < 64) {
      int q = t >> 1, p = t & 1;
      const double* L = base + ((size_t)q * NSLt + 2 * p) * KNN;
      LOADB16(L)
      LOADC16(L + 16)
      MERGE16
      STOREB16(&mg[q][p][0])
    }
    __syncthreads();
  }
  if (t < 32) {  // final level -> sidx
    if constexpr (NSLt == 8) {
      LOADB16(&mg2[t][0][0])
      LOADC16(&mg2[t][1][0])
    } else {
      LOADB16(&mg[t][0][0])
      LOADC16(&mg[t][1][0])
    }
    MERGE16
    // OR-packed keys: idx lives in the low 12 mantissa BITS -> extract via bit-cast
    int* si = &sidx[t * 17];
    si[0] = (int)(__double_as_longlong(b0) & 4095);
    si[1] = (int)(__double_as_longlong(b1) & 4095);
    si[2] = (int)(__double_as_longlong(b2) & 4095);
    si[3] = (int)(__double_as_longlong(b3) & 4095);
    si[4] = (int)(__double_as_longlong(b4) & 4095);
    si[5] = (int)(__double_as_longlong(b5) & 4095);
    si[6] = (int)(__double_as_longlong(b6) & 4095);
    si[7] = (int)(__double_as_longlong(b7) & 4095);
    si[8] = (int)(__double_as_longlong(b8) & 4095);
    si[9] = (int)(__double_as_longlong(b9) & 4095);
    si[10] = (int)(__double_as_longlong(b10) & 4095);
    si[11] = (int)(__double_as_longlong(b11) & 4095);
    si[12] = (int)(__double_as_longlong(b12) & 4095);
    si[13] = (int)(__double_as_longlong(b13) & 4095);
    si[14] = (int)(__double_as_longlong(b14) & 4095);
    si[15] = (int)(__double_as_longlong(b15) & 4095);
  }
  __syncthreads();
  // ---- phase 2: gather + maxpool + qadd + leaky -> xs (transposed) ----
  {
    const float4* kvs = (const float4*)(ws_c + OFF_KVS) + (size_t)b * NKV * 8 + l2;
    float4 p0 = make_float4(-3.4e38f, -3.4e38f, -3.4e38f, -3.4e38f);
#pragma unroll
    for (int n = 0; n < KNN; ++n) {
      int m = sidx[q2 * 17 + n];
      float4 v0 = kvs[(size_t)m * 8];
      p0.x = fmaxf(p0.x, v0.x); p0.y = fmaxf(p0.y, v0.y);
      p0.z = fmaxf(p0.z, v0.z); p0.w = fmaxf(p0.w, v0.w);
    }
    int h0 = 4 * l2;
    xs[(h0 + 0) * 33 + q2] = leaky(p0.x + av.x);
    xs[(h0 + 1) * 33 + q2] = leaky(p0.y + av.y);
    xs[(h0 + 2) * 33 + q2] = leaky(p0.z + av.z);
    xs[(h0 + 3) * 33 + q2] = leaky(p0.w + av.w);
  }
  __syncthreads();
  // ---- phase 3: y = leaky(w2t · x + b2f) ----
  {
    int ql = t & 31, cb = t >> 5;  // cb half-wave-uniform -> w2t loads L1-broadcast
    const float* w2t = (const float*)(ws_c + OFF_W2T);
    const float* b2f = (const float*)(ws_c + OFF_B2F);
    float xv[Hh];
#pragma unroll
    for (int h = 0; h < Hh; ++h) xv[h] = xs[h * 33 + ql];
    float4 acc[8];
#pragma unroll
    for (int c4 = 0; c4 < 8; ++c4) acc[c4] = make_float4(0.f, 0.f, 0.f, 0.f);
#pragma unroll
    for (int h = 0; h < Hh; ++h) {
      float xh = xv[h];
      const float4* wrow = (const float4*)(w2t + (size_t)h * Cc + cb * 32);
#pragma unroll
      for (int c4 = 0; c4 < 8; ++c4) {
        float4 w = wrow[c4];
        acc[c4].x = fmaf(xh, w.x, acc[c4].x);
        acc[c4].y = fmaf(xh, w.y, acc[c4].y);
        acc[c4].z = fmaf(xh, w.z, acc[c4].z);
        acc[c4].w = fmaf(xh, w.w, acc[c4].w);
      }
    }
    float* o = out + ((size_t)b * NQ + q0 + ql) * Cc + cb * 32;
    const float4* bb = (const float4*)(b2f + cb * 32);
#pragma unroll
    for (int c4 = 0; c4 < 8; ++c4) {
      float4 bv = bb[c4];
      float4 r;
      r.x = leaky(acc[c4].x + bv.x); r.y = leaky(acc[c4].y + bv.y);
      r.z = leaky(acc[c4].z + bv.z); r.w = leaky(acc[c4].w + bv.w);
      *(float4*)(o + c4 * 4) = r;
    }
  }
}

extern "C" void kernel_launch(void* const* d_in, const int* in_sizes, int n_in,
                              void* d_out, int out_size, void* d_ws, size_t ws_size,
                              hipStream_t stream) {
  const float* qf   = (const float*)d_in[0];
  const float* qxyz = (const float*)d_in[1];
  const float* kvf  = (const float*)d_in[2];
  const float* kxyz = (const float*)d_in[3];
  const float* w1 = (const float*)d_in[4];
  const float* g1 = (const float*)d_in[5];
  const float* b1 = (const float*)d_in[6];
  const float* m1 = (const float*)d_in[7];
  const float* v1 = (const float*)d_in[8];
  const float* w2 = (const float*)d_in[9];
  const float* g2 = (const float*)d_in[10];
  const float* b2 = (const float*)d_in[11];
  const float* m2 = (const float*)d_in[12];
  const float* v2 = (const float*)d_in[13];
  char* ws = (char*)d_ws;
  double* pd = (double*)(ws + OFF_PD);

  // NSL=8 needs OFF_PD + 8*4096*8*16*8 = ~42.5 MB of ws; fall back to NSL=4 otherwise.
  size_t need8 = (size_t)OFF_PD + (size_t)Bz * NQ * 8 * KNN * sizeof(double);
  bool big = ws_size >= need8;

  k_prep<<<129, 256, 0, stream>>>(qxyz, kxyz, w1, g1, b1, m1, v1, w2, g2, b2, m2, v2, ws);
  if (big) {
    k_sel<512><<<dim3(NQ / 256, 8, Bz), 256, 0, stream>>>(ws, pd);
    k_feat<<<dim3(NKV / 128, Bz, 2), 256, 0, stream>>>(kvf, qf, ws, ws);
    k_tail<8><<<dim3(NQ / 32, Bz), 256, 0, stream>>>(pd, ws, (float*)d_out);
  } else {
    k_sel<1024><<<dim3(NQ / 256, 4, Bz), 256, 0, stream>>>(ws, pd);
    k_feat<<<dim3(NKV / 128, Bz, 2), 256, 0, stream>>>(kvf, qf, ws, ws);
    k_tail<4><<<dim3(NQ / 32, Bz), 256, 0, stream>>>(pd, ws, (float*)d_out);
  }
}